// Round 1
// baseline (693.409 us; speedup 1.0000x reference)
//
#include <hip/hip_runtime.h>
#include <hip/hip_bf16.h>
#include <math.h>

#define IN_DIM 256
#define OUT_DIM 128
#define LEAKY 0.2f

// wcomb[0:256] = W_src @ a[0:128]   (for score_i = src @ wcomb_lo)
__global__ __launch_bounds__(256) void combine_w_kernel(
    const float* __restrict__ W_src, const float* __restrict__ a,
    float* __restrict__ wcomb) {
    int i = blockIdx.x * blockDim.x + threadIdx.x;  // 0..255
    if (i < 256) {
        float s = 0.f;
        #pragma unroll 4
        for (int k = 0; k < OUT_DIM; ++k) s += W_src[i * OUT_DIM + k] * a[k];
        wcomb[i] = s;
    }
}

__global__ __launch_bounds__(256) void gemv_score_kernel(
    const float* __restrict__ X, const float* __restrict__ w,
    float* __restrict__ score, int M) {
    int wid = (int)((blockIdx.x * (long long)blockDim.x + threadIdx.x) >> 6);
    int lane = threadIdx.x & 63;
    if (wid >= M) return;
    const float4* row = (const float4*)(X + (size_t)wid * IN_DIM);
    float4 x = row[lane];
    float4 wv = ((const float4*)w)[lane];
    float s = x.x * wv.x + x.y * wv.y + x.z * wv.z + x.w * wv.w;
    #pragma unroll
    for (int d = 1; d < 64; d <<= 1) s += __shfl_xor(s, d);
    if (lane == 0) score[wid] = s;
}

#define BM 64
#define BN 128
#define BK 32
__global__ __launch_bounds__(256) void gemm_score_kernel(
    const float* __restrict__ A, const float* __restrict__ W,
    const float* __restrict__ a_hi, float* __restrict__ H,
    float* __restrict__ score, int M) {
    __shared__ float As[BM][BK + 1];
    __shared__ float Bs[BK][BN];
    int tid = threadIdx.x;
    int bm = blockIdx.x * BM;
    int ty = tid >> 4;
    int tx = tid & 15;
    float acc[4][8];
    #pragma unroll
    for (int i = 0; i < 4; ++i)
        #pragma unroll
        for (int j = 0; j < 8; ++j) acc[i][j] = 0.f;

    int ar = tid >> 3;
    int ac4 = (tid & 7) * 4;
    int br = tid >> 5;
    int bc4 = (tid & 31) * 4;

    for (int k0 = 0; k0 < IN_DIM; k0 += BK) {
        #pragma unroll
        for (int p = 0; p < 2; ++p) {
            int row = ar + p * 32;
            int grow = bm + row;
            float4 v = make_float4(0.f, 0.f, 0.f, 0.f);
            if (grow < M) v = *(const float4*)(A + (size_t)grow * IN_DIM + k0 + ac4);
            As[row][ac4 + 0] = v.x; As[row][ac4 + 1] = v.y;
            As[row][ac4 + 2] = v.z; As[row][ac4 + 3] = v.w;
        }
        #pragma unroll
        for (int p = 0; p < 4; ++p) {
            int row = br + p * 8;
            float4 v = *(const float4*)(W + (size_t)(k0 + row) * BN + bc4);
            *(float4*)&Bs[row][bc4] = v;
        }
        __syncthreads();
        #pragma unroll
        for (int kk = 0; kk < BK; ++kk) {
            float af[4], bf[8];
            #pragma unroll
            for (int i = 0; i < 4; ++i) af[i] = As[ty * 4 + i][kk];
            #pragma unroll
            for (int j = 0; j < 8; ++j) bf[j] = Bs[kk][tx * 8 + j];
            #pragma unroll
            for (int i = 0; i < 4; ++i)
                #pragma unroll
                for (int j = 0; j < 8; ++j) acc[i][j] += af[i] * bf[j];
        }
        __syncthreads();
    }
    float av[8];
    #pragma unroll
    for (int j = 0; j < 8; ++j) av[j] = a_hi[tx * 8 + j];
    #pragma unroll
    for (int i = 0; i < 4; ++i) {
        int row = bm + ty * 4 + i;
        if (row < M) {
            float4 v0 = make_float4(acc[i][0], acc[i][1], acc[i][2], acc[i][3]);
            float4 v1 = make_float4(acc[i][4], acc[i][5], acc[i][6], acc[i][7]);
            *(float4*)(H + (size_t)row * BN + tx * 8) = v0;
            *(float4*)(H + (size_t)row * BN + tx * 8 + 4) = v1;
            float s = 0.f;
            #pragma unroll
            for (int j = 0; j < 8; ++j) s += acc[i][j] * av[j];
            s += __shfl_xor(s, 1); s += __shfl_xor(s, 2);
            s += __shfl_xor(s, 4); s += __shfl_xor(s, 8);
            if (tx == 0) score[row] = s;
        }
    }
}

__global__ __launch_bounds__(256) void edge_pass1_kernel(
    const int* __restrict__ src_id, const int* __restrict__ tgt_id,
    const float* __restrict__ score_i, const float* __restrict__ score_j,
    float* __restrict__ exp_e, float* __restrict__ denom, int E) {
    int e = blockIdx.x * blockDim.x + threadIdx.x;
    if (e >= E) return;
    int s = src_id[e], t = tgt_id[e];
    float x = score_i[s] + score_j[t];
    x = x > 0.f ? x : LEAKY * x;
    x = fminf(30.f, fmaxf(-30.f, x));
    float ex = expf(x);
    exp_e[e] = ex;
    atomicAdd(&denom[s], ex);
}

__global__ __launch_bounds__(256) void edge_pass2_kernel(
    const int* __restrict__ src_id, const int* __restrict__ tgt_id,
    const float* __restrict__ hj, const float* __restrict__ exp_e,
    const float* __restrict__ denom, float* __restrict__ out, int E) {
    int idx = blockIdx.x * blockDim.x + threadIdx.x;
    int e = idx >> 6;
    if (e >= E) return;
    int lane = idx & 63;
    int s = src_id[e], t = tgt_id[e];
    float alpha = exp_e[e] / (denom[s] + 1e-8f);
    float2 h = *(const float2*)(hj + (size_t)t * OUT_DIM + lane * 2);
    atomicAdd(out + (size_t)s * OUT_DIM + lane * 2 + 0, h.x * alpha);
    atomicAdd(out + (size_t)s * OUT_DIM + lane * 2 + 1, h.y * alpha);
}

__global__ __launch_bounds__(256) void elu_kernel(float* __restrict__ out, int n4) {
    int i = blockIdx.x * blockDim.x + threadIdx.x;
    if (i >= n4) return;
    float4 v = ((float4*)out)[i];
    v.x = v.x > 0.f ? v.x : expm1f(v.x);
    v.y = v.y > 0.f ? v.y : expm1f(v.y);
    v.z = v.z > 0.f ? v.z : expm1f(v.z);
    v.w = v.w > 0.f ? v.w : expm1f(v.w);
    ((float4*)out)[i] = v;
}

extern "C" void kernel_launch(void* const* d_in, const int* in_sizes, int n_in,
                              void* d_out, int out_size, void* d_ws, size_t ws_size,
                              hipStream_t stream) {
    const float* src   = (const float*)d_in[0];
    const float* tgt   = (const float*)d_in[1];
    const float* W_src = (const float*)d_in[2];
    const float* W_tgt = (const float*)d_in[3];
    const float* a     = (const float*)d_in[4];
    const int*   edge  = (const int*)d_in[5];

    int N_src = in_sizes[0] / IN_DIM;
    int N_tgt = in_sizes[1] / IN_DIM;
    int E     = in_sizes[5] / 2;
    const int* src_id = edge;
    const int* tgt_id = edge + E;

    float* out = (float*)d_out;

    float* ws = (float*)d_ws;
    float* hj      = ws;
    float* score_i = hj + (size_t)N_tgt * OUT_DIM;
    float* score_j = score_i + N_src;
    float* denom   = score_j + N_tgt;
    float* exp_e   = denom + N_src;
    float* wcomb   = exp_e + E;

    hipMemsetAsync(out, 0, (size_t)N_src * OUT_DIM * sizeof(float), stream);
    hipMemsetAsync(denom, 0, (size_t)N_src * sizeof(float), stream);

    combine_w_kernel<<<1, 256, 0, stream>>>(W_src, a, wcomb);

    gemv_score_kernel<<<(N_src + 3) / 4, 256, 0, stream>>>(src, wcomb, score_i, N_src);

    gemm_score_kernel<<<(N_tgt + BM - 1) / BM, 256, 0, stream>>>(
        tgt, W_tgt, a + OUT_DIM, hj, score_j, N_tgt);

    edge_pass1_kernel<<<(E + 255) / 256, 256, 0, stream>>>(
        src_id, tgt_id, score_i, score_j, exp_e, denom, E);

    edge_pass2_kernel<<<(int)(((long long)E * 64 + 255) / 256), 256, 0, stream>>>(
        src_id, tgt_id, hj, exp_e, denom, out, E);

    elu_kernel<<<(N_src * OUT_DIM / 4 + 255) / 256, 256, 0, stream>>>(
        out, N_src * OUT_DIM / 4);
}

// Round 2
// 329.258 us; speedup vs baseline: 2.1060x; 2.1060x over previous
//
#include <hip/hip_runtime.h>
#include <hip/hip_bf16.h>
#include <math.h>

#define IN_DIM 256
#define OUT_DIM 128
#define LEAKY 0.2f

// ---------------- wcomb[0:256] = W_src @ a[0:128]
__global__ __launch_bounds__(256) void combine_w_kernel(
    const float* __restrict__ W_src, const float* __restrict__ a,
    float* __restrict__ wcomb) {
    int i = blockIdx.x * blockDim.x + threadIdx.x;
    if (i < 256) {
        float s = 0.f;
        #pragma unroll 4
        for (int k = 0; k < OUT_DIM; ++k) s += W_src[i * OUT_DIM + k] * a[k];
        wcomb[i] = s;
    }
}

// ---------------- score_i = src @ wcomb (wave per row)
__global__ __launch_bounds__(256) void gemv_score_kernel(
    const float* __restrict__ X, const float* __restrict__ w,
    float* __restrict__ score, int M) {
    int wid = (int)((blockIdx.x * (long long)blockDim.x + threadIdx.x) >> 6);
    int lane = threadIdx.x & 63;
    if (wid >= M) return;
    const float4* row = (const float4*)(X + (size_t)wid * IN_DIM);
    float4 x = row[lane];
    float4 wv = ((const float4*)w)[lane];
    float s = x.x * wv.x + x.y * wv.y + x.z * wv.z + x.w * wv.w;
    #pragma unroll
    for (int d = 1; d < 64; d <<= 1) s += __shfl_xor(s, d);
    if (lane == 0) score[wid] = s;
}

// ---------------- GEMM: H = tgt @ W_tgt, fused score_j
#define BM 64
#define BN 128
#define BK 32
__global__ __launch_bounds__(256) void gemm_score_kernel(
    const float* __restrict__ A, const float* __restrict__ W,
    const float* __restrict__ a_hi, float* __restrict__ H,
    float* __restrict__ score, int M) {
    __shared__ float As[BM][BK + 1];
    __shared__ float Bs[BK][BN];
    int tid = threadIdx.x;
    int bm = blockIdx.x * BM;
    int ty = tid >> 4;
    int tx = tid & 15;
    float acc[4][8];
    #pragma unroll
    for (int i = 0; i < 4; ++i)
        #pragma unroll
        for (int j = 0; j < 8; ++j) acc[i][j] = 0.f;

    int ar = tid >> 3;
    int ac4 = (tid & 7) * 4;
    int br = tid >> 5;
    int bc4 = (tid & 31) * 4;

    for (int k0 = 0; k0 < IN_DIM; k0 += BK) {
        #pragma unroll
        for (int p = 0; p < 2; ++p) {
            int row = ar + p * 32;
            int grow = bm + row;
            float4 v = make_float4(0.f, 0.f, 0.f, 0.f);
            if (grow < M) v = *(const float4*)(A + (size_t)grow * IN_DIM + k0 + ac4);
            As[row][ac4 + 0] = v.x; As[row][ac4 + 1] = v.y;
            As[row][ac4 + 2] = v.z; As[row][ac4 + 3] = v.w;
        }
        #pragma unroll
        for (int p = 0; p < 4; ++p) {
            int row = br + p * 8;
            float4 v = *(const float4*)(W + (size_t)(k0 + row) * BN + bc4);
            *(float4*)&Bs[row][bc4] = v;
        }
        __syncthreads();
        #pragma unroll
        for (int kk = 0; kk < BK; ++kk) {
            float af[4], bf[8];
            #pragma unroll
            for (int i = 0; i < 4; ++i) af[i] = As[ty * 4 + i][kk];
            #pragma unroll
            for (int j = 0; j < 8; ++j) bf[j] = Bs[kk][tx * 8 + j];
            #pragma unroll
            for (int i = 0; i < 4; ++i)
                #pragma unroll
                for (int j = 0; j < 8; ++j) acc[i][j] += af[i] * bf[j];
        }
        __syncthreads();
    }
    float av[8];
    #pragma unroll
    for (int j = 0; j < 8; ++j) av[j] = a_hi[tx * 8 + j];
    #pragma unroll
    for (int i = 0; i < 4; ++i) {
        int row = bm + ty * 4 + i;
        if (row < M) {
            float4 v0 = make_float4(acc[i][0], acc[i][1], acc[i][2], acc[i][3]);
            float4 v1 = make_float4(acc[i][4], acc[i][5], acc[i][6], acc[i][7]);
            *(float4*)(H + (size_t)row * BN + tx * 8) = v0;
            *(float4*)(H + (size_t)row * BN + tx * 8 + 4) = v1;
            float s = 0.f;
            #pragma unroll
            for (int j = 0; j < 8; ++j) s += acc[i][j] * av[j];
            s += __shfl_xor(s, 1); s += __shfl_xor(s, 2);
            s += __shfl_xor(s, 4); s += __shfl_xor(s, 8);
            if (tx == 0) score[row] = s;
        }
    }
}

// ---------------- edge pass 1: exp_e + denom + degree histogram
__global__ __launch_bounds__(256) void edge_pass1_kernel(
    const int* __restrict__ src_id, const int* __restrict__ tgt_id,
    const float* __restrict__ score_i, const float* __restrict__ score_j,
    float* __restrict__ exp_e, float* __restrict__ denom,
    int* __restrict__ counts, int E) {
    int e = blockIdx.x * blockDim.x + threadIdx.x;
    if (e >= E) return;
    int s = src_id[e], t = tgt_id[e];
    float x = score_i[s] + score_j[t];
    x = x > 0.f ? x : LEAKY * x;
    x = fminf(30.f, fmaxf(-30.f, x));
    float ex = expf(x);
    exp_e[e] = ex;
    atomicAdd(&denom[s], ex);
    atomicAdd(&counts[s], 1);
}

// ---------------- exclusive scan (2-level), SCAN_B = 1024 elems/block
__global__ __launch_bounds__(256) void scan1_kernel(
    const int* __restrict__ counts, int* __restrict__ offs,
    int* __restrict__ blockSums, int n) {
    __shared__ int sd[256];
    int b = blockIdx.x, tid = threadIdx.x;
    int base = b * 1024 + tid * 4;
    int v0 = base + 0 < n ? counts[base + 0] : 0;
    int v1 = base + 1 < n ? counts[base + 1] : 0;
    int v2 = base + 2 < n ? counts[base + 2] : 0;
    int v3 = base + 3 < n ? counts[base + 3] : 0;
    int p1 = v0, p2 = v0 + v1, p3 = v0 + v1 + v2;
    int tsum = p3 + v3;
    sd[tid] = tsum;
    __syncthreads();
    #pragma unroll
    for (int off = 1; off < 256; off <<= 1) {
        int t = tid >= off ? sd[tid - off] : 0;
        __syncthreads();
        sd[tid] += t;
        __syncthreads();
    }
    int ex = sd[tid] - tsum;
    if (base + 0 < n) offs[base + 0] = ex;
    if (base + 1 < n) offs[base + 1] = ex + p1;
    if (base + 2 < n) offs[base + 2] = ex + p2;
    if (base + 3 < n) offs[base + 3] = ex + p3;
    if (tid == 255) blockSums[b] = sd[255];
}

__global__ __launch_bounds__(256) void scan2_kernel(
    const int* __restrict__ blockSums, int* __restrict__ blockOffs, int nb) {
    __shared__ int sd[256];
    int tid = threadIdx.x;
    int v = tid < nb ? blockSums[tid] : 0;
    sd[tid] = v;
    __syncthreads();
    #pragma unroll
    for (int off = 1; off < 256; off <<= 1) {
        int t = tid >= off ? sd[tid - off] : 0;
        __syncthreads();
        sd[tid] += t;
        __syncthreads();
    }
    blockOffs[tid] = sd[tid] - v;
}

__global__ __launch_bounds__(256) void scan3_kernel(
    int* __restrict__ offs, const int* __restrict__ blockOffs, int n, int E) {
    int i = blockIdx.x * blockDim.x + threadIdx.x;
    if (i < n) offs[i] += blockOffs[i >> 10];
    if (i == 0) offs[n] = E;
}

// ---------------- scatter edges into CSR order
__global__ __launch_bounds__(256) void scatter_kernel(
    const int* __restrict__ src_id, const int* __restrict__ tgt_id,
    const float* __restrict__ exp_e, int* __restrict__ cursor,
    int* __restrict__ sorted_t, float* __restrict__ sorted_w, int E) {
    int e = blockIdx.x * blockDim.x + threadIdx.x;
    if (e >= E) return;
    int s = src_id[e];
    int p = atomicAdd(&cursor[s], 1);
    sorted_t[p] = tgt_id[e];
    sorted_w[p] = exp_e[e];
}

// ---------------- aggregate: one wave per src node, fused ELU
__global__ __launch_bounds__(256) void agg_kernel(
    const int* __restrict__ sorted_t, const float* __restrict__ sorted_w,
    const int* __restrict__ offs, const float* __restrict__ denom,
    const float* __restrict__ hj, float* __restrict__ out, int N) {
    int node = (int)((blockIdx.x * (long long)blockDim.x + threadIdx.x) >> 6);
    if (node >= N) return;
    int lane = threadIdx.x & 63;
    int beg = offs[node], end = offs[node + 1];
    float inv = 1.f / (denom[node] + 1e-8f);
    float acc0 = 0.f, acc1 = 0.f;
    for (int k = beg; k < end; ++k) {
        int t = sorted_t[k];
        float w = sorted_w[k] * inv;
        float2 h = *(const float2*)(hj + (size_t)t * OUT_DIM + lane * 2);
        acc0 += h.x * w;
        acc1 += h.y * w;
    }
    acc0 = acc0 > 0.f ? acc0 : expm1f(acc0);
    acc1 = acc1 > 0.f ? acc1 : expm1f(acc1);
    *(float2*)(out + (size_t)node * OUT_DIM + lane * 2) = make_float2(acc0, acc1);
}

// ---------------- fallback path (atomic scatter), used only if ws too small
__global__ __launch_bounds__(256) void edge_pass2_kernel(
    const int* __restrict__ src_id, const int* __restrict__ tgt_id,
    const float* __restrict__ hj, const float* __restrict__ exp_e,
    const float* __restrict__ denom, float* __restrict__ out, int E) {
    int idx = blockIdx.x * blockDim.x + threadIdx.x;
    int e = idx >> 6;
    if (e >= E) return;
    int lane = idx & 63;
    int s = src_id[e], t = tgt_id[e];
    float alpha = exp_e[e] / (denom[s] + 1e-8f);
    float2 h = *(const float2*)(hj + (size_t)t * OUT_DIM + lane * 2);
    atomicAdd(out + (size_t)s * OUT_DIM + lane * 2 + 0, h.x * alpha);
    atomicAdd(out + (size_t)s * OUT_DIM + lane * 2 + 1, h.y * alpha);
}

__global__ __launch_bounds__(256) void elu_kernel(float* __restrict__ out, int n4) {
    int i = blockIdx.x * blockDim.x + threadIdx.x;
    if (i >= n4) return;
    float4 v = ((float4*)out)[i];
    v.x = v.x > 0.f ? v.x : expm1f(v.x);
    v.y = v.y > 0.f ? v.y : expm1f(v.y);
    v.z = v.z > 0.f ? v.z : expm1f(v.z);
    v.w = v.w > 0.f ? v.w : expm1f(v.w);
    ((float4*)out)[i] = v;
}

extern "C" void kernel_launch(void* const* d_in, const int* in_sizes, int n_in,
                              void* d_out, int out_size, void* d_ws, size_t ws_size,
                              hipStream_t stream) {
    const float* src   = (const float*)d_in[0];
    const float* tgt   = (const float*)d_in[1];
    const float* W_src = (const float*)d_in[2];
    const float* W_tgt = (const float*)d_in[3];
    const float* a     = (const float*)d_in[4];
    const int*   edge  = (const int*)d_in[5];

    int N_src = in_sizes[0] / IN_DIM;
    int N_tgt = in_sizes[1] / IN_DIM;
    int E     = in_sizes[5] / 2;
    const int* src_id = edge;
    const int* tgt_id = edge + E;

    float* out = (float*)d_out;

    // workspace layout
    char* ws = (char*)d_ws;
    size_t off = 0;
    auto alloc_f = [&](size_t n) { float* p = (float*)(ws + off); off += n * 4; return p; };
    auto alloc_i = [&](size_t n) { int* p = (int*)(ws + off); off += n * 4; return p; };

    float* hj      = alloc_f((size_t)N_tgt * OUT_DIM);
    float* score_i = alloc_f(N_src);
    float* score_j = alloc_f(N_tgt);
    float* denom   = alloc_f(N_src);
    float* exp_e   = alloc_f(E);
    float* wcomb   = alloc_f(256);
    size_t base_need = off;
    int*   counts    = alloc_i(N_src);
    int*   offs      = alloc_i(N_src + 1);
    int*   blockSums = alloc_i(256);
    int*   blockOffs = alloc_i(256);
    int*   cursor    = alloc_i(N_src);
    int*   sorted_t  = alloc_i(E);
    float* sorted_w  = alloc_f(E);
    size_t csr_need = off;

    bool use_csr = (ws_size >= csr_need);

    hipMemsetAsync(denom, 0, (size_t)N_src * sizeof(float), stream);

    combine_w_kernel<<<1, 256, 0, stream>>>(W_src, a, wcomb);
    gemv_score_kernel<<<(N_src + 3) / 4, 256, 0, stream>>>(src, wcomb, score_i, N_src);
    gemm_score_kernel<<<(N_tgt + BM - 1) / BM, 256, 0, stream>>>(
        tgt, W_tgt, a + OUT_DIM, hj, score_j, N_tgt);

    if (use_csr) {
        hipMemsetAsync(counts, 0, (size_t)N_src * sizeof(int), stream);
        edge_pass1_kernel<<<(E + 255) / 256, 256, 0, stream>>>(
            src_id, tgt_id, score_i, score_j, exp_e, denom, counts, E);
        int nb = (N_src + 1023) / 1024;
        scan1_kernel<<<nb, 256, 0, stream>>>(counts, offs, blockSums, N_src);
        scan2_kernel<<<1, 256, 0, stream>>>(blockSums, blockOffs, nb);
        scan3_kernel<<<(N_src + 255) / 256, 256, 0, stream>>>(offs, blockOffs, N_src, E);
        hipMemcpyAsync(cursor, offs, (size_t)N_src * sizeof(int),
                       hipMemcpyDeviceToDevice, stream);
        scatter_kernel<<<(E + 255) / 256, 256, 0, stream>>>(
            src_id, tgt_id, exp_e, cursor, sorted_t, sorted_w, E);
        agg_kernel<<<(N_src + 3) / 4, 256, 0, stream>>>(
            sorted_t, sorted_w, offs, denom, hj, out, N_src);
    } else {
        // fallback: atomic scatter (needs only base_need bytes)
        (void)base_need;
        hipMemsetAsync(out, 0, (size_t)N_src * OUT_DIM * sizeof(float), stream);
        edge_pass1_kernel<<<(E + 255) / 256, 256, 0, stream>>>(
            src_id, tgt_id, score_i, score_j, exp_e, denom, counts, E);
        edge_pass2_kernel<<<(int)(((long long)E * 64 + 255) / 256), 256, 0, stream>>>(
            src_id, tgt_id, hj, exp_e, denom, out, E);
        elu_kernel<<<(N_src * OUT_DIM / 4 + 255) / 256, 256, 0, stream>>>(
            out, N_src * OUT_DIM / 4);
    }
}

// Round 3
// 275.691 us; speedup vs baseline: 2.5152x; 1.1943x over previous
//
#include <hip/hip_runtime.h>
#include <hip/hip_bf16.h>
#include <math.h>

#define IN_DIM 256
#define OUT_DIM 128
#define LEAKY 0.2f

typedef __attribute__((ext_vector_type(8))) short bf16x8;
typedef __attribute__((ext_vector_type(4))) float f32x4;

__device__ __forceinline__ unsigned short f2bf(float f) {
    union { float f; unsigned int u; } v; v.f = f;
    unsigned int r = v.u + 0x7FFFu + ((v.u >> 16) & 1u);
    return (unsigned short)(r >> 16);
}
__device__ __forceinline__ float bf2f(unsigned int hi16) {
    union { unsigned int u; float f; } v; v.u = hi16 << 16;
    return v.f;
}

// ---------------- wcomb[0:256] = W_src @ a[0:128]
__global__ __launch_bounds__(256) void combine_w_kernel(
    const float* __restrict__ W_src, const float* __restrict__ a,
    float* __restrict__ wcomb) {
    int i = blockIdx.x * blockDim.x + threadIdx.x;
    if (i < 256) {
        float s = 0.f;
        #pragma unroll 4
        for (int k = 0; k < OUT_DIM; ++k) s += W_src[i * OUT_DIM + k] * a[k];
        wcomb[i] = s;
    }
}

// ---------------- pre-swizzle W_tgt (f32 [256][128]) into bf16 fragment-major
// frag index: (kc, j, lane) -> 8 bf16 = B[k = kc*32 + (lane>>4)*8 + e][col = j*16 + (lane&15)]
__global__ __launch_bounds__(256) void wswz_kernel(
    const float* __restrict__ W, unsigned short* __restrict__ Wswz) {
    int idx = blockIdx.x * 256 + threadIdx.x;   // 0..4095
    if (idx >= 4096) return;
    int l  = idx & 63;
    int fj = (idx >> 6) & 7;
    int kc = idx >> 9;
    int col = fj * 16 + (l & 15);
    int kb  = kc * 32 + (l >> 4) * 8;
    unsigned int u[4];
    #pragma unroll
    for (int p = 0; p < 4; ++p) {
        unsigned short e0 = f2bf(W[(size_t)(kb + 2 * p + 0) * OUT_DIM + col]);
        unsigned short e1 = f2bf(W[(size_t)(kb + 2 * p + 1) * OUT_DIM + col]);
        u[p] = (unsigned int)e0 | ((unsigned int)e1 << 16);
    }
    *(uint4*)(Wswz + (size_t)idx * 8) = make_uint4(u[0], u[1], u[2], u[3]);
}

// ---------------- score_i = src @ wcomb (wave per row)
__global__ __launch_bounds__(256) void gemv_score_kernel(
    const float* __restrict__ X, const float* __restrict__ w,
    float* __restrict__ score, int M) {
    int wid = (int)((blockIdx.x * (long long)blockDim.x + threadIdx.x) >> 6);
    int lane = threadIdx.x & 63;
    if (wid >= M) return;
    const float4* row = (const float4*)(X + (size_t)wid * IN_DIM);
    float4 x = row[lane];
    float4 wv = ((const float4*)w)[lane];
    float s = x.x * wv.x + x.y * wv.y + x.z * wv.z + x.w * wv.w;
    #pragma unroll
    for (int d = 1; d < 64; d <<= 1) s += __shfl_xor(s, d);
    if (lane == 0) score[wid] = s;
}

// ---------------- MFMA GEMM: Hb = bf16(tgt @ W_tgt), fused score_j
// block: 256 thr = 4 waves; tile 128 rows x 128 cols; K-chunks of 64
__global__ __launch_bounds__(256) void gemm_mfma_kernel(
    const float* __restrict__ A,            // [M,256] f32
    const unsigned short* __restrict__ Wswz,// fragment-major bf16
    const float* __restrict__ a_hi,         // [128]
    unsigned short* __restrict__ Hb,        // [M,128] bf16
    float* __restrict__ score, int M) {
    __shared__ unsigned short As[128 * 64];  // 16 KB, XOR-swizzled
    int tid = threadIdx.x;
    int w = tid >> 6;
    int l = tid & 63;
    int bm = blockIdx.x * 128;

    float aw[8];
    #pragma unroll
    for (int j = 0; j < 8; ++j) aw[j] = a_hi[j * 16 + (l & 15)];

    f32x4 acc[2][8];
    f32x4 zero = {0.f, 0.f, 0.f, 0.f};
    #pragma unroll
    for (int wr = 0; wr < 2; ++wr)
        #pragma unroll
        for (int j = 0; j < 8; ++j) acc[wr][j] = zero;

    for (int c = 0; c < 4; ++c) {
        __syncthreads();   // protect As reuse across chunks
        // stage: rows 0..127, k in [c*64, c*64+64); thread: row=(tid>>4)+16p, fi=tid&15
        #pragma unroll
        for (int p = 0; p < 8; ++p) {
            int row = (tid >> 4) + p * 16;
            int grow = bm + row;
            float4 v = make_float4(0.f, 0.f, 0.f, 0.f);
            if (grow < M)
                v = *(const float4*)(A + (size_t)grow * IN_DIM + c * 64 + (tid & 15) * 4);
            unsigned int b0 = (unsigned int)f2bf(v.x) | ((unsigned int)f2bf(v.y) << 16);
            unsigned int b1 = (unsigned int)f2bf(v.z) | ((unsigned int)f2bf(v.w) << 16);
            unsigned int byteoff = (unsigned int)(row * 128 + (tid & 15) * 8) ^ ((row & 7) << 4);
            *(uint2*)((char*)As + byteoff) = make_uint2(b0, b1);
        }
        __syncthreads();
        #pragma unroll
        for (int s = 0; s < 2; ++s) {
            bf16x8 af[2];
            #pragma unroll
            for (int wr = 0; wr < 2; ++wr) {
                int row = w * 32 + wr * 16 + (l & 15);
                unsigned int byteoff =
                    (unsigned int)(row * 128 + s * 64 + (l >> 4) * 16) ^ ((row & 7) << 4);
                af[wr] = *(const bf16x8*)((const char*)As + byteoff);
            }
            int kc = c * 2 + s;
            #pragma unroll
            for (int j = 0; j < 8; ++j) {
                bf16x8 bf = *(const bf16x8*)(Wswz + ((size_t)(kc * 8 + j) * 64 + l) * 8);
                acc[0][j] = __builtin_amdgcn_mfma_f32_16x16x32_bf16(af[0], bf, acc[0][j], 0, 0, 0);
                acc[1][j] = __builtin_amdgcn_mfma_f32_16x16x32_bf16(af[1], bf, acc[1][j], 0, 0, 0);
            }
        }
    }
    // epilogue: C/D layout col = l&15, row = (l>>4)*4 + r
    #pragma unroll
    for (int wr = 0; wr < 2; ++wr) {
        #pragma unroll
        for (int r = 0; r < 4; ++r) {
            int row = bm + w * 32 + wr * 16 + (l >> 4) * 4 + r;
            if (row < M) {
                float s = 0.f;
                #pragma unroll
                for (int j = 0; j < 8; ++j) {
                    float v = acc[wr][j][r];
                    Hb[(size_t)row * OUT_DIM + j * 16 + (l & 15)] = f2bf(v);
                    s += v * aw[j];
                }
                s += __shfl_xor(s, 1); s += __shfl_xor(s, 2);
                s += __shfl_xor(s, 4); s += __shfl_xor(s, 8);
                if ((l & 15) == 0) score[row] = s;
            }
        }
    }
}

// ---------------- edge pass 1: exp_e + denom + degree histogram
__global__ __launch_bounds__(256) void edge_pass1_kernel(
    const int* __restrict__ src_id, const int* __restrict__ tgt_id,
    const float* __restrict__ score_i, const float* __restrict__ score_j,
    float* __restrict__ exp_e, float* __restrict__ denom,
    int* __restrict__ counts, int E) {
    int e = blockIdx.x * blockDim.x + threadIdx.x;
    if (e >= E) return;
    int s = src_id[e], t = tgt_id[e];
    float x = score_i[s] + score_j[t];
    x = x > 0.f ? x : LEAKY * x;
    x = fminf(30.f, fmaxf(-30.f, x));
    float ex = expf(x);
    exp_e[e] = ex;
    atomicAdd(&denom[s], ex);
    atomicAdd(&counts[s], 1);
}

// ---------------- 2-level exclusive scan
__global__ __launch_bounds__(256) void scan1_kernel(
    const int* __restrict__ counts, int* __restrict__ offs,
    int* __restrict__ blockSums, int n) {
    __shared__ int sd[256];
    int b = blockIdx.x, tid = threadIdx.x;
    int base = b * 1024 + tid * 4;
    int v0 = base + 0 < n ? counts[base + 0] : 0;
    int v1 = base + 1 < n ? counts[base + 1] : 0;
    int v2 = base + 2 < n ? counts[base + 2] : 0;
    int v3 = base + 3 < n ? counts[base + 3] : 0;
    int p1 = v0, p2 = v0 + v1, p3 = v0 + v1 + v2;
    int tsum = p3 + v3;
    sd[tid] = tsum;
    __syncthreads();
    #pragma unroll
    for (int off = 1; off < 256; off <<= 1) {
        int t = tid >= off ? sd[tid - off] : 0;
        __syncthreads();
        sd[tid] += t;
        __syncthreads();
    }
    int ex = sd[tid] - tsum;
    if (base + 0 < n) offs[base + 0] = ex;
    if (base + 1 < n) offs[base + 1] = ex + p1;
    if (base + 2 < n) offs[base + 2] = ex + p2;
    if (base + 3 < n) offs[base + 3] = ex + p3;
    if (tid == 255) blockSums[b] = sd[255];
}

__global__ __launch_bounds__(256) void scan2_kernel(
    const int* __restrict__ blockSums, int* __restrict__ blockOffs, int nb) {
    __shared__ int sd[256];
    int tid = threadIdx.x;
    int v = tid < nb ? blockSums[tid] : 0;
    sd[tid] = v;
    __syncthreads();
    #pragma unroll
    for (int off = 1; off < 256; off <<= 1) {
        int t = tid >= off ? sd[tid - off] : 0;
        __syncthreads();
        sd[tid] += t;
        __syncthreads();
    }
    blockOffs[tid] = sd[tid] - v;
}

__global__ __launch_bounds__(256) void scan3_kernel(
    int* __restrict__ offs, const int* __restrict__ blockOffs, int n, int E) {
    int i = blockIdx.x * blockDim.x + threadIdx.x;
    if (i < n) offs[i] += blockOffs[i >> 10];
    if (i == 0) offs[n] = E;
}

// ---------------- scatter edges into CSR order
__global__ __launch_bounds__(256) void scatter_kernel(
    const int* __restrict__ src_id, const int* __restrict__ tgt_id,
    const float* __restrict__ exp_e, int* __restrict__ cursor,
    int* __restrict__ sorted_t, float* __restrict__ sorted_w, int E) {
    int e = blockIdx.x * blockDim.x + threadIdx.x;
    if (e >= E) return;
    int s = src_id[e];
    int p = atomicAdd(&cursor[s], 1);
    sorted_t[p] = tgt_id[e];
    sorted_w[p] = exp_e[e];
}

// ---------------- aggregate: one wave per src node, fused ELU (bf16 hj)
__global__ __launch_bounds__(256) void agg_kernel(
    const int* __restrict__ sorted_t, const float* __restrict__ sorted_w,
    const int* __restrict__ offs, const float* __restrict__ denom,
    const unsigned short* __restrict__ hjb, float* __restrict__ out, int N) {
    int node = (int)((blockIdx.x * (long long)blockDim.x + threadIdx.x) >> 6);
    if (node >= N) return;
    int lane = threadIdx.x & 63;
    int beg = offs[node], end = offs[node + 1];
    float inv = 1.f / (denom[node] + 1e-8f);
    float acc0 = 0.f, acc1 = 0.f;
    for (int k = beg; k < end; ++k) {
        int t = sorted_t[k];
        float wgt = sorted_w[k] * inv;
        unsigned int u = *(const unsigned int*)(hjb + (size_t)t * OUT_DIM + lane * 2);
        acc0 += bf2f(u & 0xffffu) * wgt;
        acc1 += bf2f(u >> 16) * wgt;
    }
    acc0 = acc0 > 0.f ? acc0 : expm1f(acc0);
    acc1 = acc1 > 0.f ? acc1 : expm1f(acc1);
    *(float2*)(out + (size_t)node * OUT_DIM + lane * 2) = make_float2(acc0, acc1);
}

// ---------------- fallback path (atomic scatter) if ws too small
__global__ __launch_bounds__(256) void edge_pass2_kernel(
    const int* __restrict__ src_id, const int* __restrict__ tgt_id,
    const unsigned short* __restrict__ hjb, const float* __restrict__ exp_e,
    const float* __restrict__ denom, float* __restrict__ out, int E) {
    int idx = blockIdx.x * blockDim.x + threadIdx.x;
    int e = idx >> 6;
    if (e >= E) return;
    int lane = idx & 63;
    int s = src_id[e], t = tgt_id[e];
    float alpha = exp_e[e] / (denom[s] + 1e-8f);
    unsigned int u = *(const unsigned int*)(hjb + (size_t)t * OUT_DIM + lane * 2);
    atomicAdd(out + (size_t)s * OUT_DIM + lane * 2 + 0, bf2f(u & 0xffffu) * alpha);
    atomicAdd(out + (size_t)s * OUT_DIM + lane * 2 + 1, bf2f(u >> 16) * alpha);
}

__global__ __launch_bounds__(256) void elu_kernel(float* __restrict__ out, int n4) {
    int i = blockIdx.x * blockDim.x + threadIdx.x;
    if (i >= n4) return;
    float4 v = ((float4*)out)[i];
    v.x = v.x > 0.f ? v.x : expm1f(v.x);
    v.y = v.y > 0.f ? v.y : expm1f(v.y);
    v.z = v.z > 0.f ? v.z : expm1f(v.z);
    v.w = v.w > 0.f ? v.w : expm1f(v.w);
    ((float4*)out)[i] = v;
}

extern "C" void kernel_launch(void* const* d_in, const int* in_sizes, int n_in,
                              void* d_out, int out_size, void* d_ws, size_t ws_size,
                              hipStream_t stream) {
    const float* src   = (const float*)d_in[0];
    const float* tgt   = (const float*)d_in[1];
    const float* W_src = (const float*)d_in[2];
    const float* W_tgt = (const float*)d_in[3];
    const float* a     = (const float*)d_in[4];
    const int*   edge  = (const int*)d_in[5];

    int N_src = in_sizes[0] / IN_DIM;
    int N_tgt = in_sizes[1] / IN_DIM;
    int E     = in_sizes[5] / 2;
    const int* src_id = edge;
    const int* tgt_id = edge + E;

    float* out = (float*)d_out;

    // workspace layout (256B-aligned chunks)
    char* ws = (char*)d_ws;
    size_t off = 0;
    auto alloc = [&](size_t bytes) {
        void* p = ws + off;
        off += (bytes + 255) & ~(size_t)255;
        return p;
    };

    unsigned short* hjb  = (unsigned short*)alloc((size_t)N_tgt * OUT_DIM * 2);
    float* score_i = (float*)alloc((size_t)N_src * 4);
    float* score_j = (float*)alloc((size_t)N_tgt * 4);
    float* denom   = (float*)alloc((size_t)N_src * 4);
    float* exp_e   = (float*)alloc((size_t)E * 4);
    float* wcomb   = (float*)alloc(256 * 4);
    unsigned short* Wswz = (unsigned short*)alloc(4096 * 8 * 2);
    int*   counts    = (int*)alloc((size_t)N_src * 4);
    int*   offs      = (int*)alloc((size_t)(N_src + 1) * 4);
    int*   blockSums = (int*)alloc(256 * 4);
    int*   blockOffs = (int*)alloc(256 * 4);
    int*   cursor    = (int*)alloc((size_t)N_src * 4);
    size_t base_need = off;
    int*   sorted_t  = (int*)alloc((size_t)E * 4);
    float* sorted_w  = (float*)alloc((size_t)E * 4);
    size_t csr_need = off;

    bool use_csr = (ws_size >= csr_need);

    hipMemsetAsync(denom, 0, (size_t)N_src * sizeof(float), stream);

    combine_w_kernel<<<1, 256, 0, stream>>>(W_src, a, wcomb);
    wswz_kernel<<<16, 256, 0, stream>>>(W_tgt, Wswz);
    gemv_score_kernel<<<(N_src + 3) / 4, 256, 0, stream>>>(src, wcomb, score_i, N_src);
    gemm_mfma_kernel<<<(N_tgt + 127) / 128, 256, 0, stream>>>(
        tgt, Wswz, a + OUT_DIM, hjb, score_j, N_tgt);

    if (use_csr) {
        hipMemsetAsync(counts, 0, (size_t)N_src * sizeof(int), stream);
        edge_pass1_kernel<<<(E + 255) / 256, 256, 0, stream>>>(
            src_id, tgt_id, score_i, score_j, exp_e, denom, counts, E);
        int nb = (N_src + 1023) / 1024;
        scan1_kernel<<<nb, 256, 0, stream>>>(counts, offs, blockSums, N_src);
        scan2_kernel<<<1, 256, 0, stream>>>(blockSums, blockOffs, nb);
        scan3_kernel<<<(N_src + 255) / 256, 256, 0, stream>>>(offs, blockOffs, N_src, E);
        hipMemcpyAsync(cursor, offs, (size_t)N_src * sizeof(int),
                       hipMemcpyDeviceToDevice, stream);
        scatter_kernel<<<(E + 255) / 256, 256, 0, stream>>>(
            src_id, tgt_id, exp_e, cursor, sorted_t, sorted_w, E);
        agg_kernel<<<(N_src + 3) / 4, 256, 0, stream>>>(
            sorted_t, sorted_w, offs, denom, hjb, out, N_src);
    } else {
        (void)base_need;
        hipMemsetAsync(out, 0, (size_t)N_src * OUT_DIM * sizeof(float), stream);
        hipMemsetAsync(counts, 0, (size_t)N_src * sizeof(int), stream);
        edge_pass1_kernel<<<(E + 255) / 256, 256, 0, stream>>>(
            src_id, tgt_id, score_i, score_j, exp_e, denom, counts, E);
        edge_pass2_kernel<<<(int)(((long long)E * 64 + 255) / 256), 256, 0, stream>>>(
            src_id, tgt_id, hjb, exp_e, denom, out, E);
        elu_kernel<<<(N_src * OUT_DIM / 4 + 255) / 256, 256, 0, stream>>>(
            out, N_src * OUT_DIM / 4);
    }
}

// Round 4
// 259.153 us; speedup vs baseline: 2.6757x; 1.0638x over previous
//
#include <hip/hip_runtime.h>
#include <hip/hip_bf16.h>
#include <math.h>

#define IN_DIM 256
#define OUT_DIM 128
#define LEAKY 0.2f

typedef __attribute__((ext_vector_type(8))) short bf16x8;
typedef __attribute__((ext_vector_type(4))) float f32x4;

__device__ __forceinline__ unsigned short f2bf(float f) {
    union { float f; unsigned int u; } v; v.f = f;
    unsigned int r = v.u + 0x7FFFu + ((v.u >> 16) & 1u);
    return (unsigned short)(r >> 16);
}
__device__ __forceinline__ float bf2f(unsigned int hi16) {
    union { unsigned int u; float f; } v; v.u = hi16 << 16;
    return v.f;
}

// ---------------- wcomb[0:256] = W_src @ a[0:128]
__global__ __launch_bounds__(256) void combine_w_kernel(
    const float* __restrict__ W_src, const float* __restrict__ a,
    float* __restrict__ wcomb) {
    int i = blockIdx.x * blockDim.x + threadIdx.x;
    if (i < 256) {
        float s = 0.f;
        #pragma unroll 4
        for (int k = 0; k < OUT_DIM; ++k) s += W_src[i * OUT_DIM + k] * a[k];
        wcomb[i] = s;
    }
}

// ---------------- pre-swizzle W_tgt into bf16 fragment-major
__global__ __launch_bounds__(256) void wswz_kernel(
    const float* __restrict__ W, unsigned short* __restrict__ Wswz) {
    int idx = blockIdx.x * 256 + threadIdx.x;   // 0..4095
    if (idx >= 4096) return;
    int l  = idx & 63;
    int fj = (idx >> 6) & 7;
    int kc = idx >> 9;
    int col = fj * 16 + (l & 15);
    int kb  = kc * 32 + (l >> 4) * 8;
    unsigned int u[4];
    #pragma unroll
    for (int p = 0; p < 4; ++p) {
        unsigned short e0 = f2bf(W[(size_t)(kb + 2 * p + 0) * OUT_DIM + col]);
        unsigned short e1 = f2bf(W[(size_t)(kb + 2 * p + 1) * OUT_DIM + col]);
        u[p] = (unsigned int)e0 | ((unsigned int)e1 << 16);
    }
    *(uint4*)(Wswz + (size_t)idx * 8) = make_uint4(u[0], u[1], u[2], u[3]);
}

// ---------------- score_i = src @ wcomb (wave per row)
__global__ __launch_bounds__(256) void gemv_score_kernel(
    const float* __restrict__ X, const float* __restrict__ w,
    float* __restrict__ score, int M) {
    int wid = (int)((blockIdx.x * (long long)blockDim.x + threadIdx.x) >> 6);
    int lane = threadIdx.x & 63;
    if (wid >= M) return;
    const float4* row = (const float4*)(X + (size_t)wid * IN_DIM);
    float4 x = row[lane];
    float4 wv = ((const float4*)w)[lane];
    float s = x.x * wv.x + x.y * wv.y + x.z * wv.z + x.w * wv.w;
    #pragma unroll
    for (int d = 1; d < 64; d <<= 1) s += __shfl_xor(s, d);
    if (lane == 0) score[wid] = s;
}

// ---------------- MFMA GEMM: Hb = bf16(tgt @ W_tgt), fused score_j
// 256 thr = 4 waves; tile 64 rows x 128 cols; K-chunks of 64; dbuf LDS + reg prefetch
__global__ __launch_bounds__(256) void gemm_mfma_kernel(
    const float* __restrict__ A,            // [M,256] f32
    const unsigned short* __restrict__ Wswz,// fragment-major bf16
    const float* __restrict__ a_hi,         // [128]
    unsigned short* __restrict__ Hb,        // [M,128] bf16
    float* __restrict__ score, int M) {
    __shared__ unsigned short As[2][64 * 64];  // 2 x 8 KB, XOR-swizzled
    int tid = threadIdx.x;
    int w = tid >> 6;
    int l = tid & 63;
    int bm = blockIdx.x * 64;

    float aw[8];
    #pragma unroll
    for (int j = 0; j < 8; ++j) aw[j] = a_hi[j * 16 + (l & 15)];

    f32x4 acc[8];
    f32x4 zero = {0.f, 0.f, 0.f, 0.f};
    #pragma unroll
    for (int j = 0; j < 8; ++j) acc[j] = zero;

    int srow = tid >> 4;          // 0..15 (staging row base)
    int kcol = (tid & 15) * 4;    // 0..60 (staging k offset)

    float4 pre[4];
    // prologue: load + stage chunk 0
    #pragma unroll
    for (int p = 0; p < 4; ++p) {
        int grow = bm + srow + p * 16;
        pre[p] = (grow < M) ? *(const float4*)(A + (size_t)grow * IN_DIM + kcol)
                            : make_float4(0.f, 0.f, 0.f, 0.f);
    }
    #pragma unroll
    for (int p = 0; p < 4; ++p) {
        int row = srow + p * 16;
        unsigned int b0 = (unsigned int)f2bf(pre[p].x) | ((unsigned int)f2bf(pre[p].y) << 16);
        unsigned int b1 = (unsigned int)f2bf(pre[p].z) | ((unsigned int)f2bf(pre[p].w) << 16);
        unsigned int byteoff = (unsigned int)(row * 128 + kcol * 2) ^ ((row & 7) << 4);
        *(uint2*)((char*)&As[0][0] + byteoff) = make_uint2(b0, b1);
    }
    __syncthreads();

    for (int c = 0; c < 4; ++c) {
        // issue next chunk's global loads early (latency hides under MFMA)
        if (c < 3) {
            #pragma unroll
            for (int p = 0; p < 4; ++p) {
                int grow = bm + srow + p * 16;
                pre[p] = (grow < M)
                    ? *(const float4*)(A + (size_t)grow * IN_DIM + (c + 1) * 64 + kcol)
                    : make_float4(0.f, 0.f, 0.f, 0.f);
            }
        }
        // MFMA phase on buffer c&1
        const char* buf = (const char*)&As[c & 1][0];
        #pragma unroll
        for (int s = 0; s < 2; ++s) {
            int row = w * 16 + (l & 15);
            unsigned int byteoff =
                (unsigned int)(row * 128 + s * 64 + (l >> 4) * 16) ^ ((row & 7) << 4);
            bf16x8 af = *(const bf16x8*)(buf + byteoff);
            int kc = c * 2 + s;
            #pragma unroll
            for (int j = 0; j < 8; ++j) {
                bf16x8 bfj = *(const bf16x8*)(Wswz + ((size_t)(kc * 8 + j) * 64 + l) * 8);
                acc[j] = __builtin_amdgcn_mfma_f32_16x16x32_bf16(af, bfj, acc[j], 0, 0, 0);
            }
        }
        // write next chunk to the other buffer
        if (c < 3) {
            char* nbuf = (char*)&As[(c + 1) & 1][0];
            #pragma unroll
            for (int p = 0; p < 4; ++p) {
                int row = srow + p * 16;
                unsigned int b0 = (unsigned int)f2bf(pre[p].x) | ((unsigned int)f2bf(pre[p].y) << 16);
                unsigned int b1 = (unsigned int)f2bf(pre[p].z) | ((unsigned int)f2bf(pre[p].w) << 16);
                unsigned int byteoff = (unsigned int)(row * 128 + kcol * 2) ^ ((row & 7) << 4);
                *(uint2*)(nbuf + byteoff) = make_uint2(b0, b1);
            }
            __syncthreads();
        }
    }
    // epilogue: C/D layout col = l&15, row = (l>>4)*4 + r
    #pragma unroll
    for (int r = 0; r < 4; ++r) {
        int row = bm + w * 16 + (l >> 4) * 4 + r;
        if (row < M) {
            float s = 0.f;
            #pragma unroll
            for (int j = 0; j < 8; ++j) {
                float v = acc[j][r];
                Hb[(size_t)row * OUT_DIM + j * 16 + (l & 15)] = f2bf(v);
                s += v * aw[j];
            }
            s += __shfl_xor(s, 1); s += __shfl_xor(s, 2);
            s += __shfl_xor(s, 4); s += __shfl_xor(s, 8);
            if ((l & 15) == 0) score[row] = s;
        }
    }
}

// ---------------- degree histogram (minimal read)
__global__ __launch_bounds__(256) void hist_kernel(
    const int* __restrict__ src_id, int* __restrict__ counts, int E) {
    int e = blockIdx.x * blockDim.x + threadIdx.x;
    if (e >= E) return;
    atomicAdd(&counts[src_id[e]], 1);
}

// ---------------- 2-level exclusive scan
__global__ __launch_bounds__(256) void scan1_kernel(
    const int* __restrict__ counts, int* __restrict__ offs,
    int* __restrict__ blockSums, int n) {
    __shared__ int sd[256];
    int b = blockIdx.x, tid = threadIdx.x;
    int base = b * 1024 + tid * 4;
    int v0 = base + 0 < n ? counts[base + 0] : 0;
    int v1 = base + 1 < n ? counts[base + 1] : 0;
    int v2 = base + 2 < n ? counts[base + 2] : 0;
    int v3 = base + 3 < n ? counts[base + 3] : 0;
    int p1 = v0, p2 = v0 + v1, p3 = v0 + v1 + v2;
    int tsum = p3 + v3;
    sd[tid] = tsum;
    __syncthreads();
    #pragma unroll
    for (int off = 1; off < 256; off <<= 1) {
        int t = tid >= off ? sd[tid - off] : 0;
        __syncthreads();
        sd[tid] += t;
        __syncthreads();
    }
    int ex = sd[tid] - tsum;
    if (base + 0 < n) offs[base + 0] = ex;
    if (base + 1 < n) offs[base + 1] = ex + p1;
    if (base + 2 < n) offs[base + 2] = ex + p2;
    if (base + 3 < n) offs[base + 3] = ex + p3;
    if (tid == 255) blockSums[b] = sd[255];
}

__global__ __launch_bounds__(256) void scan2_kernel(
    const int* __restrict__ blockSums, int* __restrict__ blockOffs, int nb) {
    __shared__ int sd[256];
    int tid = threadIdx.x;
    int v = tid < nb ? blockSums[tid] : 0;
    sd[tid] = v;
    __syncthreads();
    #pragma unroll
    for (int off = 1; off < 256; off <<= 1) {
        int t = tid >= off ? sd[tid - off] : 0;
        __syncthreads();
        sd[tid] += t;
        __syncthreads();
    }
    blockOffs[tid] = sd[tid] - v;
}

__global__ __launch_bounds__(256) void scan3_kernel(
    int* __restrict__ offs, const int* __restrict__ blockOffs, int n, int E) {
    int i = blockIdx.x * blockDim.x + threadIdx.x;
    if (i < n) offs[i] += blockOffs[i >> 10];
    if (i == 0) offs[n] = E;
}

// ---------------- fused: score -> leaky -> clip -> exp -> denom + CSR scatter
__global__ __launch_bounds__(256) void scatter_fused_kernel(
    const int* __restrict__ src_id, const int* __restrict__ tgt_id,
    const float* __restrict__ score_i, const float* __restrict__ score_j,
    float* __restrict__ denom, int* __restrict__ cursor,
    int* __restrict__ sorted_t, float* __restrict__ sorted_w, int E) {
    int e = blockIdx.x * blockDim.x + threadIdx.x;
    if (e >= E) return;
    int s = src_id[e], t = tgt_id[e];
    float x = score_i[s] + score_j[t];
    x = x > 0.f ? x : LEAKY * x;
    x = fminf(30.f, fmaxf(-30.f, x));
    float ex = expf(x);
    atomicAdd(&denom[s], ex);
    int p = atomicAdd(&cursor[s], 1);
    sorted_t[p] = t;
    sorted_w[p] = ex;
}

// ---------------- aggregate: one wave per src node, fused ELU (bf16 hj)
__global__ __launch_bounds__(256) void agg_kernel(
    const int* __restrict__ sorted_t, const float* __restrict__ sorted_w,
    const int* __restrict__ offs, const float* __restrict__ denom,
    const unsigned short* __restrict__ hjb, float* __restrict__ out, int N) {
    int node = (int)((blockIdx.x * (long long)blockDim.x + threadIdx.x) >> 6);
    if (node >= N) return;
    int lane = threadIdx.x & 63;
    int beg = offs[node], end = offs[node + 1];
    float inv = 1.f / (denom[node] + 1e-8f);
    float acc0 = 0.f, acc1 = 0.f;
    for (int k = beg; k < end; ++k) {
        int t = sorted_t[k];
        float wgt = sorted_w[k] * inv;
        unsigned int u = *(const unsigned int*)(hjb + (size_t)t * OUT_DIM + lane * 2);
        acc0 += bf2f(u & 0xffffu) * wgt;
        acc1 += bf2f(u >> 16) * wgt;
    }
    acc0 = acc0 > 0.f ? acc0 : expm1f(acc0);
    acc1 = acc1 > 0.f ? acc1 : expm1f(acc1);
    *(float2*)(out + (size_t)node * OUT_DIM + lane * 2) = make_float2(acc0, acc1);
}

// ---------------- fallback path (atomic scatter) if ws too small
__global__ __launch_bounds__(256) void edge_pass1_kernel(
    const int* __restrict__ src_id, const int* __restrict__ tgt_id,
    const float* __restrict__ score_i, const float* __restrict__ score_j,
    float* __restrict__ exp_e, float* __restrict__ denom, int E) {
    int e = blockIdx.x * blockDim.x + threadIdx.x;
    if (e >= E) return;
    int s = src_id[e], t = tgt_id[e];
    float x = score_i[s] + score_j[t];
    x = x > 0.f ? x : LEAKY * x;
    x = fminf(30.f, fmaxf(-30.f, x));
    float ex = expf(x);
    exp_e[e] = ex;
    atomicAdd(&denom[s], ex);
}

__global__ __launch_bounds__(256) void edge_pass2_kernel(
    const int* __restrict__ src_id, const int* __restrict__ tgt_id,
    const unsigned short* __restrict__ hjb, const float* __restrict__ exp_e,
    const float* __restrict__ denom, float* __restrict__ out, int E) {
    int idx = blockIdx.x * blockDim.x + threadIdx.x;
    int e = idx >> 6;
    if (e >= E) return;
    int lane = idx & 63;
    int s = src_id[e], t = tgt_id[e];
    float alpha = exp_e[e] / (denom[s] + 1e-8f);
    unsigned int u = *(const unsigned int*)(hjb + (size_t)t * OUT_DIM + lane * 2);
    atomicAdd(out + (size_t)s * OUT_DIM + lane * 2 + 0, bf2f(u & 0xffffu) * alpha);
    atomicAdd(out + (size_t)s * OUT_DIM + lane * 2 + 1, bf2f(u >> 16) * alpha);
}

__global__ __launch_bounds__(256) void elu_kernel(float* __restrict__ out, int n4) {
    int i = blockIdx.x * blockDim.x + threadIdx.x;
    if (i >= n4) return;
    float4 v = ((float4*)out)[i];
    v.x = v.x > 0.f ? v.x : expm1f(v.x);
    v.y = v.y > 0.f ? v.y : expm1f(v.y);
    v.z = v.z > 0.f ? v.z : expm1f(v.z);
    v.w = v.w > 0.f ? v.w : expm1f(v.w);
    ((float4*)out)[i] = v;
}

extern "C" void kernel_launch(void* const* d_in, const int* in_sizes, int n_in,
                              void* d_out, int out_size, void* d_ws, size_t ws_size,
                              hipStream_t stream) {
    const float* src   = (const float*)d_in[0];
    const float* tgt   = (const float*)d_in[1];
    const float* W_src = (const float*)d_in[2];
    const float* W_tgt = (const float*)d_in[3];
    const float* a     = (const float*)d_in[4];
    const int*   edge  = (const int*)d_in[5];

    int N_src = in_sizes[0] / IN_DIM;
    int N_tgt = in_sizes[1] / IN_DIM;
    int E     = in_sizes[5] / 2;
    const int* src_id = edge;
    const int* tgt_id = edge + E;

    float* out = (float*)d_out;

    char* ws = (char*)d_ws;
    size_t off = 0;
    auto alloc = [&](size_t bytes) {
        void* p = ws + off;
        off += (bytes + 255) & ~(size_t)255;
        return p;
    };

    unsigned short* hjb  = (unsigned short*)alloc((size_t)N_tgt * OUT_DIM * 2);
    float* score_i = (float*)alloc((size_t)N_src * 4);
    float* score_j = (float*)alloc((size_t)N_tgt * 4);
    float* denom   = (float*)alloc((size_t)N_src * 4);
    float* exp_e   = (float*)alloc((size_t)E * 4);
    float* wcomb   = (float*)alloc(256 * 4);
    unsigned short* Wswz = (unsigned short*)alloc(4096 * 8 * 2);
    int*   counts    = (int*)alloc((size_t)N_src * 4);
    int*   offs      = (int*)alloc((size_t)(N_src + 1) * 4);
    int*   blockSums = (int*)alloc(256 * 4);
    int*   blockOffs = (int*)alloc(256 * 4);
    int*   cursor    = (int*)alloc((size_t)N_src * 4);
    int*   sorted_t  = (int*)alloc((size_t)E * 4);
    float* sorted_w  = (float*)alloc((size_t)E * 4);
    size_t csr_need = off;

    bool use_csr = (ws_size >= csr_need);

    hipMemsetAsync(denom, 0, (size_t)N_src * sizeof(float), stream);

    combine_w_kernel<<<1, 256, 0, stream>>>(W_src, a, wcomb);
    wswz_kernel<<<16, 256, 0, stream>>>(W_tgt, Wswz);
    gemv_score_kernel<<<(N_src + 3) / 4, 256, 0, stream>>>(src, wcomb, score_i, N_src);
    gemm_mfma_kernel<<<(N_tgt + 63) / 64, 256, 0, stream>>>(
        tgt, Wswz, a + OUT_DIM, hjb, score_j, N_tgt);

    if (use_csr) {
        hipMemsetAsync(counts, 0, (size_t)N_src * sizeof(int), stream);
        hist_kernel<<<(E + 255) / 256, 256, 0, stream>>>(src_id, counts, E);
        int nb = (N_src + 1023) / 1024;
        scan1_kernel<<<nb, 256, 0, stream>>>(counts, offs, blockSums, N_src);
        scan2_kernel<<<1, 256, 0, stream>>>(blockSums, blockOffs, nb);
        scan3_kernel<<<(N_src + 255) / 256, 256, 0, stream>>>(offs, blockOffs, N_src, E);
        hipMemcpyAsync(cursor, offs, (size_t)N_src * sizeof(int),
                       hipMemcpyDeviceToDevice, stream);
        scatter_fused_kernel<<<(E + 255) / 256, 256, 0, stream>>>(
            src_id, tgt_id, score_i, score_j, denom, cursor, sorted_t, sorted_w, E);
        agg_kernel<<<(N_src + 3) / 4, 256, 0, stream>>>(
            sorted_t, sorted_w, offs, denom, hjb, out, N_src);
    } else {
        hipMemsetAsync(out, 0, (size_t)N_src * OUT_DIM * sizeof(float), stream);
        edge_pass1_kernel<<<(E + 255) / 256, 256, 0, stream>>>(
            src_id, tgt_id, score_i, score_j, exp_e, denom, E);
        edge_pass2_kernel<<<(int)(((long long)E * 64 + 255) / 256), 256, 0, stream>>>(
            src_id, tgt_id, hjb, exp_e, denom, out, E);
        elu_kernel<<<(N_src * OUT_DIM / 4 + 255) / 256, 256, 0, stream>>>(
            out, N_src * OUT_DIM / 4);
    }
}

// Round 7
// 238.196 us; speedup vs baseline: 2.9111x; 1.0880x over previous
//
#include <hip/hip_runtime.h>
#include <hip/hip_bf16.h>
#include <math.h>

#define IN_DIM 256
#define OUT_DIM 128
#define LEAKY 0.2f

typedef __attribute__((ext_vector_type(8))) short bf16x8;
typedef __attribute__((ext_vector_type(4))) float f32x4;

__device__ __forceinline__ unsigned short f2bf(float f) {
    union { float f; unsigned int u; } v; v.f = f;
    unsigned int r = v.u + 0x7FFFu + ((v.u >> 16) & 1u);
    return (unsigned short)(r >> 16);
}
__device__ __forceinline__ float bf2f(unsigned int hi16) {
    union { unsigned int u; float f; } v; v.u = hi16 << 16;
    return v.f;
}

// ---------------- wcomb[0:256] = W_src @ a[0:128]
__global__ __launch_bounds__(256) void combine_w_kernel(
    const float* __restrict__ W_src, const float* __restrict__ a,
    float* __restrict__ wcomb) {
    int i = blockIdx.x * blockDim.x + threadIdx.x;
    if (i < 256) {
        float s = 0.f;
        #pragma unroll 4
        for (int k = 0; k < OUT_DIM; ++k) s += W_src[i * OUT_DIM + k] * a[k];
        wcomb[i] = s;
    }
}

// ---------------- pre-swizzle W_tgt into bf16 fragment-major
__global__ __launch_bounds__(256) void wswz_kernel(
    const float* __restrict__ W, unsigned short* __restrict__ Wswz) {
    int idx = blockIdx.x * 256 + threadIdx.x;   // 0..4095
    if (idx >= 4096) return;
    int l  = idx & 63;
    int fj = (idx >> 6) & 7;
    int kc = idx >> 9;
    int col = fj * 16 + (l & 15);
    int kb  = kc * 32 + (l >> 4) * 8;
    unsigned int u[4];
    #pragma unroll
    for (int p = 0; p < 4; ++p) {
        unsigned short e0 = f2bf(W[(size_t)(kb + 2 * p + 0) * OUT_DIM + col]);
        unsigned short e1 = f2bf(W[(size_t)(kb + 2 * p + 1) * OUT_DIM + col]);
        u[p] = (unsigned int)e0 | ((unsigned int)e1 << 16);
    }
    *(uint4*)(Wswz + (size_t)idx * 8) = make_uint4(u[0], u[1], u[2], u[3]);
}

// ---------------- score_i = src @ wcomb (wave per row)
__global__ __launch_bounds__(256) void gemv_score_kernel(
    const float* __restrict__ X, const float* __restrict__ w,
    float* __restrict__ score, int M) {
    int wid = (int)((blockIdx.x * (long long)blockDim.x + threadIdx.x) >> 6);
    int lane = threadIdx.x & 63;
    if (wid >= M) return;
    const float4* row = (const float4*)(X + (size_t)wid * IN_DIM);
    float4 x = row[lane];
    float4 wv = ((const float4*)w)[lane];
    float s = x.x * wv.x + x.y * wv.y + x.z * wv.z + x.w * wv.w;
    #pragma unroll
    for (int d = 1; d < 64; d <<= 1) s += __shfl_xor(s, d);
    if (lane == 0) score[wid] = s;
}

// ---------------- MFMA GEMM (round-4 proven version): Hb = bf16(tgt @ W_tgt), fused score_j
// 256 thr = 4 waves; tile 64 rows x 128 cols; K-chunks of 64; dbuf LDS + reg prefetch
__global__ __launch_bounds__(256) void gemm_mfma_kernel(
    const float* __restrict__ A,            // [M,256] f32
    const unsigned short* __restrict__ Wswz,// fragment-major bf16
    const float* __restrict__ a_hi,         // [128]
    unsigned short* __restrict__ Hb,        // [M,128] bf16
    float* __restrict__ score, int M) {
    __shared__ unsigned short As[2][64 * 64];  // 2 x 8 KB, XOR-swizzled
    int tid = threadIdx.x;
    int w = tid >> 6;
    int l = tid & 63;
    int bm = blockIdx.x * 64;

    float aw[8];
    #pragma unroll
    for (int j = 0; j < 8; ++j) aw[j] = a_hi[j * 16 + (l & 15)];

    f32x4 acc[8];
    f32x4 zero = {0.f, 0.f, 0.f, 0.f};
    #pragma unroll
    for (int j = 0; j < 8; ++j) acc[j] = zero;

    int srow = tid >> 4;          // 0..15 (staging row base)
    int kcol = (tid & 15) * 4;    // 0..60 (staging k offset)

    float4 pre[4];
    // prologue: load + stage chunk 0
    #pragma unroll
    for (int p = 0; p < 4; ++p) {
        int grow = bm + srow + p * 16;
        pre[p] = (grow < M) ? *(const float4*)(A + (size_t)grow * IN_DIM + kcol)
                            : make_float4(0.f, 0.f, 0.f, 0.f);
    }
    #pragma unroll
    for (int p = 0; p < 4; ++p) {
        int row = srow + p * 16;
        unsigned int b0 = (unsigned int)f2bf(pre[p].x) | ((unsigned int)f2bf(pre[p].y) << 16);
        unsigned int b1 = (unsigned int)f2bf(pre[p].z) | ((unsigned int)f2bf(pre[p].w) << 16);
        unsigned int byteoff = (unsigned int)(row * 128 + kcol * 2) ^ ((row & 7) << 4);
        *(uint2*)((char*)&As[0][0] + byteoff) = make_uint2(b0, b1);
    }
    __syncthreads();

    for (int c = 0; c < 4; ++c) {
        // issue next chunk's global loads early (latency hides under MFMA)
        if (c < 3) {
            #pragma unroll
            for (int p = 0; p < 4; ++p) {
                int grow = bm + srow + p * 16;
                pre[p] = (grow < M)
                    ? *(const float4*)(A + (size_t)grow * IN_DIM + (c + 1) * 64 + kcol)
                    : make_float4(0.f, 0.f, 0.f, 0.f);
            }
        }
        // MFMA phase on buffer c&1
        const char* buf = (const char*)&As[c & 1][0];
        #pragma unroll
        for (int s = 0; s < 2; ++s) {
            int row = w * 16 + (l & 15);
            unsigned int byteoff =
                (unsigned int)(row * 128 + s * 64 + (l >> 4) * 16) ^ ((row & 7) << 4);
            bf16x8 af = *(const bf16x8*)(buf + byteoff);
            int kc = c * 2 + s;
            #pragma unroll
            for (int j = 0; j < 8; ++j) {
                bf16x8 bfj = *(const bf16x8*)(Wswz + ((size_t)(kc * 8 + j) * 64 + l) * 8);
                acc[j] = __builtin_amdgcn_mfma_f32_16x16x32_bf16(af, bfj, acc[j], 0, 0, 0);
            }
        }
        // write next chunk to the other buffer
        if (c < 3) {
            char* nbuf = (char*)&As[(c + 1) & 1][0];
            #pragma unroll
            for (int p = 0; p < 4; ++p) {
                int row = srow + p * 16;
                unsigned int b0 = (unsigned int)f2bf(pre[p].x) | ((unsigned int)f2bf(pre[p].y) << 16);
                unsigned int b1 = (unsigned int)f2bf(pre[p].z) | ((unsigned int)f2bf(pre[p].w) << 16);
                unsigned int byteoff = (unsigned int)(row * 128 + kcol * 2) ^ ((row & 7) << 4);
                *(uint2*)(nbuf + byteoff) = make_uint2(b0, b1);
            }
            __syncthreads();
        }
    }
    // epilogue: C/D layout col = l&15, row = (l>>4)*4 + r
    #pragma unroll
    for (int r = 0; r < 4; ++r) {
        int row = bm + w * 16 + (l >> 4) * 4 + r;
        if (row < M) {
            float s = 0.f;
            #pragma unroll
            for (int j = 0; j < 8; ++j) {
                float v = acc[j][r];
                Hb[(size_t)row * OUT_DIM + j * 16 + (l & 15)] = f2bf(v);
                s += v * aw[j];
            }
            s += __shfl_xor(s, 1); s += __shfl_xor(s, 2);
            s += __shfl_xor(s, 4); s += __shfl_xor(s, 8);
            if ((l & 15) == 0) score[row] = s;
        }
    }
}

// ---------------- degree histogram
__global__ __launch_bounds__(256) void hist_kernel(
    const int* __restrict__ src_id, int* __restrict__ counts, int E) {
    int e = blockIdx.x * blockDim.x + threadIdx.x;
    if (e >= E) return;
    atomicAdd(&counts[src_id[e]], 1);
}

// ---------------- 2-level exclusive scan
__global__ __launch_bounds__(256) void scan1_kernel(
    const int* __restrict__ counts, int* __restrict__ offs,
    int* __restrict__ blockSums, int n) {
    __shared__ int sd[256];
    int b = blockIdx.x, tid = threadIdx.x;
    int base = b * 1024 + tid * 4;
    int v0 = base + 0 < n ? counts[base + 0] : 0;
    int v1 = base + 1 < n ? counts[base + 1] : 0;
    int v2 = base + 2 < n ? counts[base + 2] : 0;
    int v3 = base + 3 < n ? counts[base + 3] : 0;
    int p1 = v0, p2 = v0 + v1, p3 = v0 + v1 + v2;
    int tsum = p3 + v3;
    sd[tid] = tsum;
    __syncthreads();
    #pragma unroll
    for (int off = 1; off < 256; off <<= 1) {
        int t = tid >= off ? sd[tid - off] : 0;
        __syncthreads();
        sd[tid] += t;
        __syncthreads();
    }
    int ex = sd[tid] - tsum;
    if (base + 0 < n) offs[base + 0] = ex;
    if (base + 1 < n) offs[base + 1] = ex + p1;
    if (base + 2 < n) offs[base + 2] = ex + p2;
    if (base + 3 < n) offs[base + 3] = ex + p3;
    if (tid == 255) blockSums[b] = sd[255];
}

__global__ __launch_bounds__(256) void scan2_kernel(
    const int* __restrict__ blockSums, int* __restrict__ blockOffs, int nb) {
    __shared__ int sd[256];
    int tid = threadIdx.x;
    int v = tid < nb ? blockSums[tid] : 0;
    sd[tid] = v;
    __syncthreads();
    #pragma unroll
    for (int off = 1; off < 256; off <<= 1) {
        int t = tid >= off ? sd[tid - off] : 0;
        __syncthreads();
        sd[tid] += t;
        __syncthreads();
    }
    blockOffs[tid] = sd[tid] - v;
}

__global__ __launch_bounds__(256) void scan3_kernel(
    int* __restrict__ offs, const int* __restrict__ blockOffs, int n, int E) {
    int i = blockIdx.x * blockDim.x + threadIdx.x;
    if (i < n) offs[i] += blockOffs[i >> 10];
    if (i == 0) offs[n] = E;
}

// ---------------- fused: score -> leaky -> clip -> exp -> denom + CSR scatter
__global__ __launch_bounds__(256) void scatter_fused_kernel(
    const int* __restrict__ src_id, const int* __restrict__ tgt_id,
    const float* __restrict__ score_i, const float* __restrict__ score_j,
    float* __restrict__ denom, int* __restrict__ cursor,
    int* __restrict__ sorted_t, float* __restrict__ sorted_w, int E) {
    int e = blockIdx.x * blockDim.x + threadIdx.x;
    if (e >= E) return;
    int s = src_id[e], t = tgt_id[e];
    float x = score_i[s] + score_j[t];
    x = x > 0.f ? x : LEAKY * x;
    x = fminf(30.f, fmaxf(-30.f, x));
    float ex = expf(x);
    atomicAdd(&denom[s], ex);
    int p = atomicAdd(&cursor[s], 1);
    sorted_t[p] = t;
    sorted_w[p] = ex;
}

// ---------------- aggregate: wave per node, 4 edges in flight, fused ELU
// Quarter-group q handles edges e ≡ q (mod 4) by DIRECT load (same addr within
// the 16-lane group -> HW broadcast). No cross-lane ops in the hot loop;
// trip count wave-uniform; invalid iterations contribute wgt = 0.
__global__ __launch_bounds__(256) void agg_kernel(
    const int* __restrict__ sorted_t, const float* __restrict__ sorted_w,
    const int* __restrict__ offs, const float* __restrict__ denom,
    const unsigned short* __restrict__ hjb, float* __restrict__ out, int N) {
    int node = (int)((blockIdx.x * (long long)blockDim.x + threadIdx.x) >> 6);
    if (node >= N) return;
    int lane = threadIdx.x & 63;
    int q  = lane >> 4;   // quarter-group
    int cl = lane & 15;   // column lane: owns cols cl*8 .. cl*8+7
    int beg = offs[node], end = offs[node + 1];
    int deg = end - beg;
    float inv = 1.f / (denom[node] + 1e-8f);
    float acc[8];
    #pragma unroll
    for (int i = 0; i < 8; ++i) acc[i] = 0.f;

    int iters = (deg + 3) >> 2;               // uniform across the wave
    for (int it = 0; it < iters; ++it) {
        int e = q + 4 * it;
        bool valid = e < deg;
        int idx = beg + (valid ? e : 0);
        int t = sorted_t[idx];
        float wgt = valid ? sorted_w[idx] * inv : 0.f;
        uint4 u = *(const uint4*)(hjb + (size_t)t * OUT_DIM + cl * 8);
        acc[0] += bf2f(u.x & 0xffffu) * wgt;
        acc[1] += bf2f(u.x >> 16) * wgt;
        acc[2] += bf2f(u.y & 0xffffu) * wgt;
        acc[3] += bf2f(u.y >> 16) * wgt;
        acc[4] += bf2f(u.z & 0xffffu) * wgt;
        acc[5] += bf2f(u.z >> 16) * wgt;
        acc[6] += bf2f(u.w & 0xffffu) * wgt;
        acc[7] += bf2f(u.w >> 16) * wgt;
    }
    #pragma unroll
    for (int i = 0; i < 8; ++i) {
        acc[i] += __shfl_xor(acc[i], 16);
        acc[i] += __shfl_xor(acc[i], 32);
        acc[i] = acc[i] > 0.f ? acc[i] : expm1f(acc[i]);
    }
    if (lane < 16) {
        float4 v0 = make_float4(acc[0], acc[1], acc[2], acc[3]);
        float4 v1 = make_float4(acc[4], acc[5], acc[6], acc[7]);
        *(float4*)(out + (size_t)node * OUT_DIM + cl * 8) = v0;
        *(float4*)(out + (size_t)node * OUT_DIM + cl * 8 + 4) = v1;
    }
}

// ---------------- fallback path (atomic scatter) if ws too small
__global__ __launch_bounds__(256) void edge_pass1_kernel(
    const int* __restrict__ src_id, const int* __restrict__ tgt_id,
    const float* __restrict__ score_i, const float* __restrict__ score_j,
    float* __restrict__ exp_e, float* __restrict__ denom, int E) {
    int e = blockIdx.x * blockDim.x + threadIdx.x;
    if (e >= E) return;
    int s = src_id[e], t = tgt_id[e];
    float x = score_i[s] + score_j[t];
    x = x > 0.f ? x : LEAKY * x;
    x = fminf(30.f, fmaxf(-30.f, x));
    float ex = expf(x);
    exp_e[e] = ex;
    atomicAdd(&denom[s], ex);
}

__global__ __launch_bounds__(256) void edge_pass2_kernel(
    const int* __restrict__ src_id, const int* __restrict__ tgt_id,
    const unsigned short* __restrict__ hjb, const float* __restrict__ exp_e,
    const float* __restrict__ denom, float* __restrict__ out, int E) {
    int idx = blockIdx.x * blockDim.x + threadIdx.x;
    int e = idx >> 6;
    if (e >= E) return;
    int lane = idx & 63;
    int s = src_id[e], t = tgt_id[e];
    float alpha = exp_e[e] / (denom[s] + 1e-8f);
    unsigned int u = *(const unsigned int*)(hjb + (size_t)t * OUT_DIM + lane * 2);
    atomicAdd(out + (size_t)s * OUT_DIM + lane * 2 + 0, bf2f(u & 0xffffu) * alpha);
    atomicAdd(out + (size_t)s * OUT_DIM + lane * 2 + 1, bf2f(u >> 16) * alpha);
}

__global__ __launch_bounds__(256) void elu_kernel(float* __restrict__ out, int n4) {
    int i = blockIdx.x * blockDim.x + threadIdx.x;
    if (i >= n4) return;
    float4 v = ((float4*)out)[i];
    v.x = v.x > 0.f ? v.x : expm1f(v.x);
    v.y = v.y > 0.f ? v.y : expm1f(v.y);
    v.z = v.z > 0.f ? v.z : expm1f(v.z);
    v.w = v.w > 0.f ? v.w : expm1f(v.w);
    ((float4*)out)[i] = v;
}

extern "C" void kernel_launch(void* const* d_in, const int* in_sizes, int n_in,
                              void* d_out, int out_size, void* d_ws, size_t ws_size,
                              hipStream_t stream) {
    const float* src   = (const float*)d_in[0];
    const float* tgt   = (const float*)d_in[1];
    const float* W_src = (const float*)d_in[2];
    const float* W_tgt = (const float*)d_in[3];
    const float* a     = (const float*)d_in[4];
    const int*   edge  = (const int*)d_in[5];

    int N_src = in_sizes[0] / IN_DIM;
    int N_tgt = in_sizes[1] / IN_DIM;
    int E     = in_sizes[5] / 2;
    const int* src_id = edge;
    const int* tgt_id = edge + E;

    float* out = (float*)d_out;

    char* ws = (char*)d_ws;
    size_t off = 0;
    auto alloc = [&](size_t bytes) {
        void* p = ws + off;
        off += (bytes + 255) & ~(size_t)255;
        return p;
    };

    unsigned short* hjb  = (unsigned short*)alloc((size_t)N_tgt * OUT_DIM * 2);
    float* score_i = (float*)alloc((size_t)N_src * 4);
    float* score_j = (float*)alloc((size_t)N_tgt * 4);
    float* denom   = (float*)alloc((size_t)N_src * 4);
    float* exp_e   = (float*)alloc((size_t)E * 4);
    float* wcomb   = (float*)alloc(256 * 4);
    unsigned short* Wswz = (unsigned short*)alloc(4096 * 8 * 2);
    int*   counts    = (int*)alloc((size_t)N_src * 4);
    int*   offs      = (int*)alloc((size_t)(N_src + 1) * 4);
    int*   blockSums = (int*)alloc(256 * 4);
    int*   blockOffs = (int*)alloc(256 * 4);
    int*   cursor    = (int*)alloc((size_t)N_src * 4);
    int*   sorted_t  = (int*)alloc((size_t)E * 4);
    float* sorted_w  = (float*)alloc((size_t)E * 4);
    size_t csr_need = off;

    bool use_csr = (ws_size >= csr_need);

    hipMemsetAsync(denom, 0, (size_t)N_src * sizeof(float), stream);

    combine_w_kernel<<<1, 256, 0, stream>>>(W_src, a, wcomb);
    wswz_kernel<<<16, 256, 0, stream>>>(W_tgt, Wswz);
    gemv_score_kernel<<<(N_src + 3) / 4, 256, 0, stream>>>(src, wcomb, score_i, N_src);
    gemm_mfma_kernel<<<(N_tgt + 63) / 64, 256, 0, stream>>>(
        tgt, Wswz, a + OUT_DIM, hjb, score_j, N_tgt);

    if (use_csr) {
        hipMemsetAsync(counts, 0, (size_t)N_src * sizeof(int), stream);
        hist_kernel<<<(E + 255) / 256, 256, 0, stream>>>(src_id, counts, E);
        int nb = (N_src + 1023) / 1024;
        scan1_kernel<<<nb, 256, 0, stream>>>(counts, offs, blockSums, N_src);
        scan2_kernel<<<1, 256, 0, stream>>>(blockSums, blockOffs, nb);
        scan3_kernel<<<(N_src + 255) / 256, 256, 0, stream>>>(offs, blockOffs, N_src, E);
        hipMemcpyAsync(cursor, offs, (size_t)N_src * sizeof(int),
                       hipMemcpyDeviceToDevice, stream);
        scatter_fused_kernel<<<(E + 255) / 256, 256, 0, stream>>>(
            src_id, tgt_id, score_i, score_j, denom, cursor, sorted_t, sorted_w, E);
        agg_kernel<<<(N_src + 3) / 4, 256, 0, stream>>>(
            sorted_t, sorted_w, offs, denom, hjb, out, N_src);
    } else {
        hipMemsetAsync(out, 0, (size_t)N_src * OUT_DIM * sizeof(float), stream);
        edge_pass1_kernel<<<(E + 255) / 256, 256, 0, stream>>>(
            src_id, tgt_id, score_i, score_j, exp_e, denom, E);
        edge_pass2_kernel<<<(int)(((long long)E * 64 + 255) / 256), 256, 0, stream>>>(
            src_id, tgt_id, hjb, exp_e, denom, out, E);
        elu_kernel<<<(N_src * OUT_DIM / 4 + 255) / 256, 256, 0, stream>>>(
            out, N_src * OUT_DIM / 4);
    }
}

// Round 8
// 175.199 us; speedup vs baseline: 3.9578x; 1.3596x over previous
//
#include <hip/hip_runtime.h>
#include <hip/hip_bf16.h>
#include <math.h>

#define IN_DIM 256
#define OUT_DIM 128
#define LEAKY 0.2f

typedef __attribute__((ext_vector_type(8))) short bf16x8;
typedef __attribute__((ext_vector_type(4))) float f32x4;

__device__ __forceinline__ unsigned short f2bf(float f) {
    union { float f; unsigned int u; } v; v.f = f;
    unsigned int r = v.u + 0x7FFFu + ((v.u >> 16) & 1u);
    return (unsigned short)(r >> 16);
}
__device__ __forceinline__ float bf2f(unsigned int hi16) {
    union { unsigned int u; float f; } v; v.u = hi16 << 16;
    return v.f;
}

// ---------------- wcomb[0:256] = W_src @ a[0:128]
__global__ __launch_bounds__(256) void combine_w_kernel(
    const float* __restrict__ W_src, const float* __restrict__ a,
    float* __restrict__ wcomb) {
    int i = blockIdx.x * blockDim.x + threadIdx.x;
    if (i < 256) {
        float s = 0.f;
        #pragma unroll 4
        for (int k = 0; k < OUT_DIM; ++k) s += W_src[i * OUT_DIM + k] * a[k];
        wcomb[i] = s;
    }
}

// ---------------- pre-swizzle W_tgt into bf16 fragment-major
__global__ __launch_bounds__(256) void wswz_kernel(
    const float* __restrict__ W, unsigned short* __restrict__ Wswz) {
    int idx = blockIdx.x * 256 + threadIdx.x;   // 0..4095
    if (idx >= 4096) return;
    int l  = idx & 63;
    int fj = (idx >> 6) & 7;
    int kc = idx >> 9;
    int col = fj * 16 + (l & 15);
    int kb  = kc * 32 + (l >> 4) * 8;
    unsigned int u[4];
    #pragma unroll
    for (int p = 0; p < 4; ++p) {
        unsigned short e0 = f2bf(W[(size_t)(kb + 2 * p + 0) * OUT_DIM + col]);
        unsigned short e1 = f2bf(W[(size_t)(kb + 2 * p + 1) * OUT_DIM + col]);
        u[p] = (unsigned int)e0 | ((unsigned int)e1 << 16);
    }
    *(uint4*)(Wswz + (size_t)idx * 8) = make_uint4(u[0], u[1], u[2], u[3]);
}

// ---------------- score_i = src @ wcomb (wave per row)
__global__ __launch_bounds__(256) void gemv_score_kernel(
    const float* __restrict__ X, const float* __restrict__ w,
    float* __restrict__ score, int M) {
    int wid = (int)((blockIdx.x * (long long)blockDim.x + threadIdx.x) >> 6);
    int lane = threadIdx.x & 63;
    if (wid >= M) return;
    const float4* row = (const float4*)(X + (size_t)wid * IN_DIM);
    float4 x = row[lane];
    float4 wv = ((const float4*)w)[lane];
    float s = x.x * wv.x + x.y * wv.y + x.z * wv.z + x.w * wv.w;
    #pragma unroll
    for (int d = 1; d < 64; d <<= 1) s += __shfl_xor(s, d);
    if (lane == 0) score[wid] = s;
}

// ---------------- MFMA GEMM: single-phase full-K staging (32 KB LDS, 1 barrier)
// 256 thr = 4 waves; tile 64 rows x 128 cols; 16 global loads in flight/thread.
// Addressing identical to the round-4-proven kernel (row stride 128B -> 512B).
__global__ __launch_bounds__(256) void gemm_mfma_kernel(
    const float* __restrict__ A,            // [M,256] f32
    const unsigned short* __restrict__ Wswz,// fragment-major bf16
    const float* __restrict__ a_hi,         // [128]
    unsigned short* __restrict__ Hb,        // [M,128] bf16
    float* __restrict__ score, int M) {
    __shared__ unsigned short As[64 * 256];  // 32 KB, XOR-swizzled
    int tid = threadIdx.x;
    int w = tid >> 6;
    int l = tid & 63;
    int bm = blockIdx.x * 64;

    int srow = tid >> 4;          // 0..15 (staging row base)
    int kcol = (tid & 15) * 4;    // 0..60 (staging k offset within 64-chunk)

    float aw[8];
    #pragma unroll
    for (int j = 0; j < 8; ++j) aw[j] = a_hi[j * 16 + (l & 15)];

    f32x4 acc[8];
    f32x4 zero = {0.f, 0.f, 0.f, 0.f};
    #pragma unroll
    for (int j = 0; j < 8; ++j) acc[j] = zero;

    // issue ALL staging loads (maximum MLP), then convert+write, one barrier
    float4 pre[16];
    #pragma unroll
    for (int p = 0; p < 4; ++p) {
        int grow = bm + srow + p * 16;
        const float* rp = A + (size_t)(grow < M ? grow : M - 1) * IN_DIM;
        bool ok = grow < M;
        #pragma unroll
        for (int c = 0; c < 4; ++c) {
            float4 v = *(const float4*)(rp + c * 64 + kcol);
            pre[p * 4 + c] = ok ? v : make_float4(0.f, 0.f, 0.f, 0.f);
        }
    }
    #pragma unroll
    for (int p = 0; p < 4; ++p) {
        int row = srow + p * 16;
        #pragma unroll
        for (int c = 0; c < 4; ++c) {
            float4 v = pre[p * 4 + c];
            unsigned int b0 = (unsigned int)f2bf(v.x) | ((unsigned int)f2bf(v.y) << 16);
            unsigned int b1 = (unsigned int)f2bf(v.z) | ((unsigned int)f2bf(v.w) << 16);
            unsigned int byteoff =
                (unsigned int)(row * 512 + (c * 64 + kcol) * 2) ^ ((row & 7) << 4);
            *(uint2*)((char*)As + byteoff) = make_uint2(b0, b1);
        }
    }
    __syncthreads();

    #pragma unroll
    for (int kc = 0; kc < 8; ++kc) {
        int row = w * 16 + (l & 15);
        unsigned int byteoff =
            (unsigned int)(row * 512 + kc * 64 + (l >> 4) * 16) ^ ((row & 7) << 4);
        bf16x8 af = *(const bf16x8*)((const char*)As + byteoff);
        #pragma unroll
        for (int j = 0; j < 8; ++j) {
            bf16x8 bfj = *(const bf16x8*)(Wswz + ((size_t)(kc * 8 + j) * 64 + l) * 8);
            acc[j] = __builtin_amdgcn_mfma_f32_16x16x32_bf16(af, bfj, acc[j], 0, 0, 0);
        }
    }
    // epilogue: C/D layout col = l&15, row = (l>>4)*4 + r
    #pragma unroll
    for (int r = 0; r < 4; ++r) {
        int row = bm + w * 16 + (l >> 4) * 4 + r;
        if (row < M) {
            float s = 0.f;
            #pragma unroll
            for (int j = 0; j < 8; ++j) {
                float v = acc[j][r];
                Hb[(size_t)row * OUT_DIM + j * 16 + (l & 15)] = f2bf(v);
                s += v * aw[j];
            }
            s += __shfl_xor(s, 1); s += __shfl_xor(s, 2);
            s += __shfl_xor(s, 4); s += __shfl_xor(s, 8);
            if ((l & 15) == 0) score[row] = s;
        }
    }
}

// ---------------- histogram + per-edge rank (the ONLY atomics in the pipeline)
__global__ __launch_bounds__(256) void hist_rank_kernel(
    const int* __restrict__ src_id, int* __restrict__ counts,
    int* __restrict__ rank, int E) {
    int e = blockIdx.x * blockDim.x + threadIdx.x;
    if (e >= E) return;
    rank[e] = atomicAdd(&counts[src_id[e]], 1);
}

// ---------------- 2-level exclusive scan
__global__ __launch_bounds__(256) void scan1_kernel(
    const int* __restrict__ counts, int* __restrict__ offs,
    int* __restrict__ blockSums, int n) {
    __shared__ int sd[256];
    int b = blockIdx.x, tid = threadIdx.x;
    int base = b * 1024 + tid * 4;
    int v0 = base + 0 < n ? counts[base + 0] : 0;
    int v1 = base + 1 < n ? counts[base + 1] : 0;
    int v2 = base + 2 < n ? counts[base + 2] : 0;
    int v3 = base + 3 < n ? counts[base + 3] : 0;
    int p1 = v0, p2 = v0 + v1, p3 = v0 + v1 + v2;
    int tsum = p3 + v3;
    sd[tid] = tsum;
    __syncthreads();
    #pragma unroll
    for (int off = 1; off < 256; off <<= 1) {
        int t = tid >= off ? sd[tid - off] : 0;
        __syncthreads();
        sd[tid] += t;
        __syncthreads();
    }
    int ex = sd[tid] - tsum;
    if (base + 0 < n) offs[base + 0] = ex;
    if (base + 1 < n) offs[base + 1] = ex + p1;
    if (base + 2 < n) offs[base + 2] = ex + p2;
    if (base + 3 < n) offs[base + 3] = ex + p3;
    if (tid == 255) blockSums[b] = sd[255];
}

__global__ __launch_bounds__(256) void scan2_kernel(
    const int* __restrict__ blockSums, int* __restrict__ blockOffs, int nb) {
    __shared__ int sd[256];
    int tid = threadIdx.x;
    int v = tid < nb ? blockSums[tid] : 0;
    sd[tid] = v;
    __syncthreads();
    #pragma unroll
    for (int off = 1; off < 256; off <<= 1) {
        int t = tid >= off ? sd[tid - off] : 0;
        __syncthreads();
        sd[tid] += t;
        __syncthreads();
    }
    blockOffs[tid] = sd[tid] - v;
}

__global__ __launch_bounds__(256) void scan3_kernel(
    int* __restrict__ offs, const int* __restrict__ blockOffs, int n, int E) {
    int i = blockIdx.x * blockDim.x + threadIdx.x;
    if (i < n) offs[i] += blockOffs[i >> 10];
    if (i == 0) offs[n] = E;
}

// ---------------- fused scatter, ZERO atomics: p = offs[s] + rank[e], packed 8B write
__global__ __launch_bounds__(256) void scatter_fused_kernel(
    const int* __restrict__ src_id, const int* __restrict__ tgt_id,
    const float* __restrict__ score_i, const float* __restrict__ score_j,
    const int* __restrict__ offs, const int* __restrict__ rank,
    uint2* __restrict__ pairs, int E) {
    int e = blockIdx.x * blockDim.x + threadIdx.x;
    if (e >= E) return;
    int s = src_id[e], t = tgt_id[e];
    float x = score_i[s] + score_j[t];
    x = x > 0.f ? x : LEAKY * x;
    x = fminf(30.f, fmaxf(-30.f, x));
    float ex = expf(x);
    int p = offs[s] + rank[e];
    pairs[p] = make_uint2((unsigned int)t, __float_as_uint(ex));
}

// ---------------- aggregate: wave per node, 4 edges in flight, inline denom, fused ELU
__global__ __launch_bounds__(256) void agg_kernel(
    const uint2* __restrict__ pairs, const int* __restrict__ offs,
    const unsigned short* __restrict__ hjb, float* __restrict__ out, int N) {
    int node = (int)((blockIdx.x * (long long)blockDim.x + threadIdx.x) >> 6);
    if (node >= N) return;
    int lane = threadIdx.x & 63;
    int q  = lane >> 4;   // quarter-group: edges e ≡ q (mod 4)
    int cl = lane & 15;   // column lane: owns cols cl*8 .. cl*8+7
    int beg = offs[node], end = offs[node + 1];
    int deg = end - beg;
    float den = 0.f;
    float acc[8];
    #pragma unroll
    for (int i = 0; i < 8; ++i) acc[i] = 0.f;

    int iters = (deg + 3) >> 2;               // uniform across the wave
    for (int it = 0; it < iters; ++it) {
        int e = q + 4 * it;
        bool valid = e < deg;
        int idx = beg + (valid ? e : 0);
        uint2 tw = pairs[idx];                // same addr in 16-lane group -> broadcast
        int t = (int)tw.x;
        float wgt = valid ? __uint_as_float(tw.y) : 0.f;
        den += wgt;
        uint4 u = *(const uint4*)(hjb + (size_t)t * OUT_DIM + cl * 8);
        acc[0] += bf2f(u.x & 0xffffu) * wgt;
        acc[1] += bf2f(u.x >> 16) * wgt;
        acc[2] += bf2f(u.y & 0xffffu) * wgt;
        acc[3] += bf2f(u.y >> 16) * wgt;
        acc[4] += bf2f(u.z & 0xffffu) * wgt;
        acc[5] += bf2f(u.z >> 16) * wgt;
        acc[6] += bf2f(u.w & 0xffffu) * wgt;
        acc[7] += bf2f(u.w >> 16) * wgt;
    }
    den += __shfl_xor(den, 16);
    den += __shfl_xor(den, 32);
    float inv = 1.f / (den + 1e-8f);
    #pragma unroll
    for (int i = 0; i < 8; ++i) {
        acc[i] += __shfl_xor(acc[i], 16);
        acc[i] += __shfl_xor(acc[i], 32);
        acc[i] *= inv;
        acc[i] = acc[i] > 0.f ? acc[i] : expm1f(acc[i]);
    }
    if (lane < 16) {
        float4 v0 = make_float4(acc[0], acc[1], acc[2], acc[3]);
        float4 v1 = make_float4(acc[4], acc[5], acc[6], acc[7]);
        *(float4*)(out + (size_t)node * OUT_DIM + cl * 8) = v0;
        *(float4*)(out + (size_t)node * OUT_DIM + cl * 8 + 4) = v1;
    }
}

// ---------------- fallback path (atomic scatter) if ws too small
__global__ __launch_bounds__(256) void edge_pass1_kernel(
    const int* __restrict__ src_id, const int* __restrict__ tgt_id,
    const float* __restrict__ score_i, const float* __restrict__ score_j,
    float* __restrict__ exp_e, float* __restrict__ denom, int E) {
    int e = blockIdx.x * blockDim.x + threadIdx.x;
    if (e >= E) return;
    int s = src_id[e], t = tgt_id[e];
    float x = score_i[s] + score_j[t];
    x = x > 0.f ? x : LEAKY * x;
    x = fminf(30.f, fmaxf(-30.f, x));
    float ex = expf(x);
    exp_e[e] = ex;
    atomicAdd(&denom[s], ex);
}

__global__ __launch_bounds__(256) void edge_pass2_kernel(
    const int* __restrict__ src_id, const int* __restrict__ tgt_id,
    const unsigned short* __restrict__ hjb, const float* __restrict__ exp_e,
    const float* __restrict__ denom, float* __restrict__ out, int E) {
    int idx = blockIdx.x * blockDim.x + threadIdx.x;
    int e = idx >> 6;
    if (e >= E) return;
    int lane = idx & 63;
    int s = src_id[e], t = tgt_id[e];
    float alpha = exp_e[e] / (denom[s] + 1e-8f);
    unsigned int u = *(const unsigned int*)(hjb + (size_t)t * OUT_DIM + lane * 2);
    atomicAdd(out + (size_t)s * OUT_DIM + lane * 2 + 0, bf2f(u & 0xffffu) * alpha);
    atomicAdd(out + (size_t)s * OUT_DIM + lane * 2 + 1, bf2f(u >> 16) * alpha);
}

__global__ __launch_bounds__(256) void elu_kernel(float* __restrict__ out, int n4) {
    int i = blockIdx.x * blockDim.x + threadIdx.x;
    if (i >= n4) return;
    float4 v = ((float4*)out)[i];
    v.x = v.x > 0.f ? v.x : expm1f(v.x);
    v.y = v.y > 0.f ? v.y : expm1f(v.y);
    v.z = v.z > 0.f ? v.z : expm1f(v.z);
    v.w = v.w > 0.f ? v.w : expm1f(v.w);
    ((float4*)out)[i] = v;
}

extern "C" void kernel_launch(void* const* d_in, const int* in_sizes, int n_in,
                              void* d_out, int out_size, void* d_ws, size_t ws_size,
                              hipStream_t stream) {
    const float* src   = (const float*)d_in[0];
    const float* tgt   = (const float*)d_in[1];
    const float* W_src = (const float*)d_in[2];
    const float* W_tgt = (const float*)d_in[3];
    const float* a     = (const float*)d_in[4];
    const int*   edge  = (const int*)d_in[5];

    int N_src = in_sizes[0] / IN_DIM;
    int N_tgt = in_sizes[1] / IN_DIM;
    int E     = in_sizes[5] / 2;
    const int* src_id = edge;
    const int* tgt_id = edge + E;

    float* out = (float*)d_out;

    char* ws = (char*)d_ws;
    size_t off = 0;
    auto alloc = [&](size_t bytes) {
        void* p = ws + off;
        off += (bytes + 255) & ~(size_t)255;
        return p;
    };

    unsigned short* hjb  = (unsigned short*)alloc((size_t)N_tgt * OUT_DIM * 2);
    float* score_i = (float*)alloc((size_t)N_src * 4);
    float* score_j = (float*)alloc((size_t)N_tgt * 4);
    float* wcomb   = (float*)alloc(256 * 4);
    unsigned short* Wswz = (unsigned short*)alloc(4096 * 8 * 2);
    int*   counts    = (int*)alloc((size_t)N_src * 4);
    int*   offs      = (int*)alloc((size_t)(N_src + 1) * 4);
    int*   blockSums = (int*)alloc(256 * 4);
    int*   blockOffs = (int*)alloc(256 * 4);
    float* denom     = (float*)alloc((size_t)N_src * 4);   // fallback only
    float* exp_e     = (float*)alloc((size_t)E * 4);       // fallback only
    size_t fb_need = off;
    int*   rank      = (int*)alloc((size_t)E * 4);
    uint2* pairs     = (uint2*)alloc((size_t)E * 8);
    size_t csr_need = off;
    (void)fb_need;

    bool use_csr = (ws_size >= csr_need);

    combine_w_kernel<<<1, 256, 0, stream>>>(W_src, a, wcomb);
    wswz_kernel<<<16, 256, 0, stream>>>(W_tgt, Wswz);
    gemv_score_kernel<<<(N_src + 3) / 4, 256, 0, stream>>>(src, wcomb, score_i, N_src);
    gemm_mfma_kernel<<<(N_tgt + 63) / 64, 256, 0, stream>>>(
        tgt, Wswz, a + OUT_DIM, hjb, score_j, N_tgt);

    if (use_csr) {
        hipMemsetAsync(counts, 0, (size_t)N_src * sizeof(int), stream);
        hist_rank_kernel<<<(E + 255) / 256, 256, 0, stream>>>(src_id, counts, rank, E);
        int nb = (N_src + 1023) / 1024;
        scan1_kernel<<<nb, 256, 0, stream>>>(counts, offs, blockSums, N_src);
        scan2_kernel<<<1, 256, 0, stream>>>(blockSums, blockOffs, nb);
        scan3_kernel<<<(N_src + 255) / 256, 256, 0, stream>>>(offs, blockOffs, N_src, E);
        scatter_fused_kernel<<<(E + 255) / 256, 256, 0, stream>>>(
            src_id, tgt_id, score_i, score_j, offs, rank, pairs, E);
        agg_kernel<<<(N_src + 3) / 4, 256, 0, stream>>>(
            pairs, offs, hjb, out, N_src);
    } else {
        hipMemsetAsync(out, 0, (size_t)N_src * OUT_DIM * sizeof(float), stream);
        hipMemsetAsync(denom, 0, (size_t)N_src * sizeof(float), stream);
        edge_pass1_kernel<<<(E + 255) / 256, 256, 0, stream>>>(
            src_id, tgt_id, score_i, score_j, exp_e, denom, E);
        edge_pass2_kernel<<<(int)(((long long)E * 64 + 255) / 256), 256, 0, stream>>>(
            src_id, tgt_id, hjb, exp_e, denom, out, E);
        elu_kernel<<<(N_src * OUT_DIM / 4 + 255) / 256, 256, 0, stream>>>(
            out, N_src * OUT_DIM / 4);
    }
}